// Round 13
// baseline (232.106 us; speedup 1.0000x reference)
//
#include <hip/hip_runtime.h>
#include <stdint.h>

// ---------------------------------------------------------------------------
// GraphAttentionLayer fused pipeline, MI355X (gfx950)
// B=64 S=512 C=512 H=4 D=128.  Split-bf16 (hi+lo) 3-term MFMA for GEMM/QK^T.
// Round 13: attn restructured to 2-wave (128-thread) blocks, 32 q per wave
// (nf=0,1).  Halves the per-block LDS read redundancy (K frags + tr_reads
// shared across nf instead of re-read by 4 waves).  3 blocks/CU (52KB pad),
// round-12 sync hardening kept throughout.
// ---------------------------------------------------------------------------

typedef float  f32x4   __attribute__((ext_vector_type(4)));
typedef short  bf16x8  __attribute__((ext_vector_type(8)));
typedef unsigned short ushort8 __attribute__((ext_vector_type(8)));
typedef unsigned int   uint2v  __attribute__((ext_vector_type(2)));

#define GLD16(src, dst)                                                        \
  __builtin_amdgcn_global_load_lds(                                            \
      (const __attribute__((address_space(1))) void*)(src),                    \
      (__attribute__((address_space(3))) void*)(dst), 16, 0, 0)

__device__ __forceinline__ unsigned short f32_to_bf16(float x) {
  union { float f; unsigned int u; } v; v.f = x;
  unsigned int r = v.u + 0x7FFFu + ((v.u >> 16) & 1u);
  return (unsigned short)(r >> 16);
}
__device__ __forceinline__ float bf16_to_f32(unsigned int h) {
  union { float f; unsigned int u; } v; v.u = h << 16;
  return v.f;
}
__device__ __forceinline__ f32x4 mfma16(bf16x8 a, bf16x8 b, f32x4 c) {
  return __builtin_amdgcn_mfma_f32_16x16x32_bf16(a, b, c, 0, 0, 0);
}
__device__ __forceinline__ float bperm_f(int srcLane, float v) {
  return __int_as_float(__builtin_amdgcn_ds_bpermute(srcLane << 2, __float_as_int(v)));
}
// HW transpose read, canonical per-lane b64 address (base + lane*8B).
__device__ __forceinline__ uint2v tr_read(const unsigned short* p) {
  uint2v r;
  asm volatile("ds_read_b64_tr_b16 %0, %1"
               : "=v"(r)
               : "v"((const __attribute__((address_space(3))) void*)p)
               : "memory");
  return r;
}

// ---------------------------------------------------------------------------
// Kernel 1: split h (fp32) -> h_hi, h_lo (bf16).  8 elems/thread.
// ---------------------------------------------------------------------------
__global__ __launch_bounds__(256) void cast_split_h(
    const float* __restrict__ src, unsigned short* __restrict__ dhi,
    unsigned short* __restrict__ dlo) {
  size_t i = ((size_t)blockIdx.x * 256 + threadIdx.x) * 8;
  f32x4 a = *(const f32x4*)(src + i);
  f32x4 b = *(const f32x4*)(src + i + 4);
  ushort8 hi, lo;
#pragma unroll
  for (int e = 0; e < 4; ++e) {
    unsigned short h0 = f32_to_bf16(a[e]);
    hi[e] = h0; lo[e] = f32_to_bf16(a[e] - bf16_to_f32(h0));
    unsigned short h1 = f32_to_bf16(b[e]);
    hi[4 + e] = h1; lo[4 + e] = f32_to_bf16(b[e] - bf16_to_f32(h1));
  }
  *(ushort8*)(dhi + i) = hi;
  *(ushort8*)(dlo + i) = lo;
}

// ---------------------------------------------------------------------------
// Kernel 2: W [H,C,D] fp32 -> Wt_hi/lo [H,D,C] bf16 (transposed per head).
// ---------------------------------------------------------------------------
__global__ __launch_bounds__(256) void cast_split_Wt(
    const float* __restrict__ W, unsigned short* __restrict__ whi,
    unsigned short* __restrict__ wlo) {
  int o = blockIdx.x * 256 + threadIdx.x;      // [0, 4*128*512)
  int hd = o >> 16;                             // head
  int rem = o & 65535;
  int d = rem >> 9;                             // [0,128)
  int c = rem & 511;                            // [0,512)
  float v = W[((size_t)(hd * 512 + c)) * 128 + d];
  unsigned short h0 = f32_to_bf16(v);
  whi[o] = h0;
  wlo[o] = f32_to_bf16(v - bf16_to_f32(h0));
}

// ---------------------------------------------------------------------------
// Kernel 2b: adj (fp32) -> bf16 (exact for 0/1 masks).  8 elems/thread.
// ---------------------------------------------------------------------------
__global__ __launch_bounds__(256) void cast_adj(
    const float* __restrict__ src, unsigned short* __restrict__ dst) {
  size_t i = ((size_t)blockIdx.x * 256 + threadIdx.x) * 8;
  f32x4 a = *(const f32x4*)(src + i);
  f32x4 b = *(const f32x4*)(src + i + 4);
  ushort8 o;
#pragma unroll
  for (int e = 0; e < 4; ++e) {
    o[e] = f32_to_bf16(a[e]);
    o[4 + e] = f32_to_bf16(b[e]);
  }
  *(ushort8*)(dst + i) = o;
}

// ---------------------------------------------------------------------------
// Kernel 3: projection GEMM  hp = h @ Wall + bias   ([32768x512]@[512x512])
// split-bf16 3-term.  128x128 tile, BK=32, 4 waves (2x2), 16x16x32 MFMA.
// ---------------------------------------------------------------------------
__global__ __launch_bounds__(256, 2) void proj_gemm(
    const unsigned short* __restrict__ ahi, const unsigned short* __restrict__ alo,
    const unsigned short* __restrict__ whi, const unsigned short* __restrict__ wlo,
    const float* __restrict__ bias, unsigned short* __restrict__ hp_hi,
    unsigned short* __restrict__ hp_lo) {
  int bid = blockIdx.x;
  int swz = (bid & 7) * 128 + (bid >> 3);       // XCD-contiguous work chunks
  int nt = swz & 3, mt = swz >> 2;
  int m0 = mt * 128, n0 = nt * 128;             // n-tile == head nt

  __shared__ alignas(16) unsigned short Ah[128 * 32], Al[128 * 32];
  __shared__ alignas(16) unsigned short Bh[128 * 32], Bl[128 * 32];

  int tid = threadIdx.x, wv = tid >> 6, lane = tid & 63;
  int l15 = lane & 15, l4 = lane >> 4;
  int wr = wv >> 1, wc = wv & 1;

  f32x4 acc[4][4];
#pragma unroll
  for (int a = 0; a < 4; ++a)
#pragma unroll
    for (int b = 0; b < 4; ++b) acc[a][b] = (f32x4){0.f, 0.f, 0.f, 0.f};

  for (int ks = 0; ks < 16; ++ks) {
    int k0 = ks * 32;
    for (int i = wv; i < 32; i += 4) {
      int grp = i >> 3, j = i & 7;
      int row = j * 16 + (lane >> 2);
      int off = (lane & 3) * 16;
      int sw = ((row >> 1) & 3) << 4;
      const unsigned short* sb;
      unsigned short* db;
      size_t srcoff;
      if (grp == 0)      { sb = ahi; db = Ah; srcoff = ((size_t)(m0 + row) * 512 + k0) * 2; }
      else if (grp == 1) { sb = alo; db = Al; srcoff = ((size_t)(m0 + row) * 512 + k0) * 2; }
      else if (grp == 2) { sb = whi; db = Bh; srcoff = ((size_t)(nt * 128 + row) * 512 + k0) * 2; }
      else               { sb = wlo; db = Bl; srcoff = ((size_t)(nt * 128 + row) * 512 + k0) * 2; }
      GLD16((const char*)sb + srcoff + (off ^ sw), db + j * 512);
    }
    __syncthreads();

    bf16x8 fah[4], fal[4], fbh[4], fbl[4];
#pragma unroll
    for (int f = 0; f < 4; ++f) {
      int mr = wr * 64 + f * 16 + l15;
      int aadr = mr * 64 + ((16 * l4) ^ (((mr >> 1) & 3) << 4));
      fah[f] = *(const bf16x8*)((const char*)Ah + aadr);
      fal[f] = *(const bf16x8*)((const char*)Al + aadr);
      int nr = wc * 64 + f * 16 + l15;
      int badr = nr * 64 + ((16 * l4) ^ (((nr >> 1) & 3) << 4));
      fbh[f] = *(const bf16x8*)((const char*)Bh + badr);
      fbl[f] = *(const bf16x8*)((const char*)Bl + badr);
    }
#pragma unroll
    for (int a = 0; a < 4; ++a)
#pragma unroll
      for (int b = 0; b < 4; ++b) {
        acc[a][b] = mfma16(fah[a], fbh[b], acc[a][b]);
        acc[a][b] = mfma16(fah[a], fbl[b], acc[a][b]);
        acc[a][b] = mfma16(fal[a], fbh[b], acc[a][b]);
      }
    __syncthreads();
  }

  // epilogue: +bias, RNE split, LDS-staged coalesced writes of hp rows.
#pragma unroll
  for (int a = 0; a < 4; ++a) {
    __syncthreads();
#pragma unroll
    for (int b = 0; b < 4; ++b) {
      int cloc = wc * 64 + b * 16 + l15;
      float bv = bias[n0 + cloc];
#pragma unroll
      for (int r = 0; r < 4; ++r) {
        int rloc = wr * 16 + 4 * l4 + r;
        float v = acc[a][b][r] + bv;
        unsigned short hh = f32_to_bf16(v);
        Ah[rloc * 128 + cloc] = hh;
        Al[rloc * 128 + cloc] = f32_to_bf16(v - bf16_to_f32(hh));
      }
    }
    __syncthreads();
    int rr = tid >> 3, c16 = (tid & 7) * 16;
    int mg = m0 + (rr >> 4) * 64 + a * 16 + (rr & 15);
    bf16x8 vh0 = *(const bf16x8*)(Ah + rr * 128 + c16);
    bf16x8 vh1 = *(const bf16x8*)(Ah + rr * 128 + c16 + 8);
    bf16x8 vl0 = *(const bf16x8*)(Al + rr * 128 + c16);
    bf16x8 vl1 = *(const bf16x8*)(Al + rr * 128 + c16 + 8);
    *(bf16x8*)(hp_hi + (size_t)mg * 512 + n0 + c16) = vh0;
    *(bf16x8*)(hp_hi + (size_t)mg * 512 + n0 + c16 + 8) = vh1;
    *(bf16x8*)(hp_lo + (size_t)mg * 512 + n0 + c16) = vl0;
    *(bf16x8*)(hp_lo + (size_t)mg * 512 + n0 + c16 + 8) = vl1;
  }
}

// ---------------------------------------------------------------------------
// Kernel 5: flash attention.  Block = (b, head, q-tile of 64), 2 waves of
// 32 q (nf=0,1 sub-frags of 16).  K subtiled [8 sd][32 kv][16 d], dbuf.
// Wave w stages K_hi (w=0) / K_lo (w=1): 8 GLD16 each.  QK^T K-frags and PV
// tr_read V-frags read ONCE per wave, shared across both nf (halved LDS
// traffic vs 4-wave).  One barrier per tile, explicit drains.  52KB pad ->
// 3 blocks/CU (12 heads/XCD = safe L2 regime).
// ---------------------------------------------------------------------------
__global__ __launch_bounds__(128, 2) void attn_kernel(
    const unsigned short* __restrict__ hp_hi, const unsigned short* __restrict__ hp_lo,
    const unsigned short* __restrict__ adjb, float* __restrict__ out) {
  int bid = blockIdx.x;
  int swz = (bid & 7) * 256 + (bid >> 3);       // 8 q-tiles of one (b,h) per XCD
  int qt = swz & 7;
  int hd = (swz >> 3) & 3;
  int bb = swz >> 5;
  int q0 = qt * 64;

  __shared__ alignas(16) unsigned short SM[26624];     // 52 KB -> 3 blocks/CU
  // buf0: K_hi @0, K_lo @4096 ; buf1: K_hi @8192, K_lo @12288  (u16 offsets)
  // each K_x = [8 sd][32 kv][16 d] subtiled (1KB per subtile)

  int tid = threadIdx.x, w = tid >> 6, lane = tid & 63;
  int l15 = lane & 15, l4 = lane >> 4;
  int qgb = q0 + w * 32 + l15;                  // + nf*16 for the softmax row

  // Q fragments (B-operand: n=q at l&15, k=d contiguous), hi+lo, 2 nf sets
  bf16x8 qh[2][4], ql[2][4];
#pragma unroll
  for (int nf = 0; nf < 2; ++nf) {
    size_t base = ((size_t)bb * 512 + qgb + nf * 16) * 512 + hd * 128 + 8 * l4;
#pragma unroll
    for (int ds = 0; ds < 4; ++ds) {
      qh[nf][ds] = *(const bf16x8*)(hp_hi + base + ds * 32);
      ql[nf][ds] = *(const bf16x8*)(hp_lo + base + ds * 32);
    }
  }

  f32x4 o[2][8];
#pragma unroll
  for (int nf = 0; nf < 2; ++nf)
#pragma unroll
    for (int vf = 0; vf < 8; ++vf) o[nf][vf] = (f32x4){0.f, 0.f, 0.f, 0.f};
  float m_run[2] = {-3.0e38f, -3.0e38f};
  float l_run[2] = {0.f, 0.f};

  // staging roles: wave 0 -> K_hi, wave 1 -> K_lo (8 GLD16 each)
  const unsigned short* ssb = w ? hp_lo : hp_hi;
  int sdst = w ? 4096 : 0;                      // u16 offset within buffer
  int skv = lane >> 1, sdh = lane & 1;          // lane i -> (kv=i>>1, dhalf)

  // ---- prologue: stage K[0] into buf0 (subtiled)
  {
    size_t rowb = ((size_t)(bb * 512 + skv)) * 1024 + hd * 256 + sdh * 16;
#pragma unroll
    for (int sd = 0; sd < 8; ++sd)
      GLD16((const char*)ssb + rowb + sd * 32, SM + sdst + sd * 512);
  }
  asm volatile("s_waitcnt vmcnt(0)" ::: "memory");
  __syncthreads();

  for (int t = 0; t < 16; ++t) {
    int kv0 = t * 32;
    const unsigned short* Kb = SM + ((t & 1) << 13);
    const unsigned short* Khi = Kb;
    const unsigned short* Klo = Kb + 4096;

    // ---- stage K[t+1] into the other buffer (drained at end-of-tile barrier)
    if (t < 15) {
      unsigned short* Nb = SM + (((t + 1) & 1) << 13) + sdst;
      size_t rowb = ((size_t)(bb * 512 + kv0 + 32 + skv)) * 1024 + hd * 256 + sdh * 16;
#pragma unroll
      for (int sd = 0; sd < 8; ++sd)
        GLD16((const char*)ssb + rowb + sd * 32, Nb + sd * 512);
    }
    // adj loads early (bf16)
    uint2 ua[2][2];
#pragma unroll
    for (int nf = 0; nf < 2; ++nf) {
      const unsigned short* ab = adjb + (size_t)(qgb + nf * 16) * 512 + kv0;
      ua[nf][0] = *(const uint2*)(ab + 4 * l4);
      ua[nf][1] = *(const uint2*)(ab + 16 + 4 * l4);
    }

    // ---- scores = K @ Q^T (swapped): K-frags read once, used by both nf
    f32x4 sc[2][2];
#pragma unroll
    for (int nf = 0; nf < 2; ++nf)
#pragma unroll
      for (int mf = 0; mf < 2; ++mf) sc[nf][mf] = (f32x4){0.f, 0.f, 0.f, 0.f};
#pragma unroll
    for (int ds = 0; ds < 4; ++ds) {
      int boff = (2 * ds + (l4 >> 1)) * 1024 + 16 * (l4 & 1);
      int a0 = boff + l15 * 32;
      int a1 = boff + (16 + l15) * 32;
      bf16x8 kh0 = *(const bf16x8*)((const char*)Khi + a0);
      bf16x8 kl0 = *(const bf16x8*)((const char*)Klo + a0);
      bf16x8 kh1 = *(const bf16x8*)((const char*)Khi + a1);
      bf16x8 kl1 = *(const bf16x8*)((const char*)Klo + a1);
#pragma unroll
      for (int nf = 0; nf < 2; ++nf) {
        sc[nf][0] = mfma16(kh0, qh[nf][ds], sc[nf][0]);
        sc[nf][1] = mfma16(kh1, qh[nf][ds], sc[nf][1]);
        sc[nf][0] = mfma16(kh0, ql[nf][ds], sc[nf][0]);
        sc[nf][1] = mfma16(kh1, ql[nf][ds], sc[nf][1]);
        sc[nf][0] = mfma16(kl0, qh[nf][ds], sc[nf][0]);
        sc[nf][1] = mfma16(kl1, qh[nf][ds], sc[nf][1]);
      }
    }

    // ---- adj multiply + online softmax + pack, per nf (independent chains)
    union PU { bf16x8 v; unsigned u[4]; } pah[2];
#pragma unroll
    for (int nf = 0; nf < 2; ++nf) {
      f32x4 av0, av1;
      av0[0] = bf16_to_f32(ua[nf][0].x & 0xFFFFu);
      av0[1] = bf16_to_f32(ua[nf][0].x >> 16);
      av0[2] = bf16_to_f32(ua[nf][0].y & 0xFFFFu);
      av0[3] = bf16_to_f32(ua[nf][0].y >> 16);
      av1[0] = bf16_to_f32(ua[nf][1].x & 0xFFFFu);
      av1[1] = bf16_to_f32(ua[nf][1].x >> 16);
      av1[2] = bf16_to_f32(ua[nf][1].y & 0xFFFFu);
      av1[3] = bf16_to_f32(ua[nf][1].y >> 16);
      float p0[4], p1[4];
      float tm = -3.0e38f;
#pragma unroll
      for (int r = 0; r < 4; ++r) {
        p0[r] = sc[nf][0][r] * av0[r];
        p1[r] = sc[nf][1][r] * av1[r];
        tm = fmaxf(tm, fmaxf(p0[r], p1[r]));
      }
      tm = fmaxf(tm, __shfl_xor(tm, 16));
      tm = fmaxf(tm, __shfl_xor(tm, 32));
      if (__any(tm > m_run[nf] + 8.0f)) {       // T13 defer-rescale
        float mn = fmaxf(m_run[nf], tm);
        float scl = __expf(m_run[nf] - mn);
        m_run[nf] = mn;
        l_run[nf] *= scl;
        f32x4 s4;
#pragma unroll
        for (int r = 0; r < 4; ++r) s4[r] = bperm_f(4 * l4 + r, scl);
#pragma unroll
        for (int vf = 0; vf < 8; ++vf)
#pragma unroll
          for (int r = 0; r < 4; ++r) o[nf][vf][r] *= s4[r];
      }
      float ps = 0.f;
#pragma unroll
      for (int r = 0; r < 4; ++r) {
        p0[r] = __expf(p0[r] - m_run[nf]); ps += p0[r];
        p1[r] = __expf(p1[r] - m_run[nf]); ps += p1[r];
      }
      ps += __shfl_xor(ps, 16);
      ps += __shfl_xor(ps, 32);
      l_run[nf] += ps;
      // pack P (trunc-bf16; denominator stays exact f32), pi-ordered
#pragma unroll
      for (int i = 0; i < 4; ++i) {
        float fa = (i < 2) ? p0[2 * i] : p1[2 * (i - 2)];
        float fb = (i < 2) ? p0[2 * i + 1] : p1[2 * (i - 2) + 1];
        pah[nf].u[i] = (__float_as_uint(fa) >> 16) |
                       (__float_as_uint(fb) & 0xFFFF0000u);
      }
    }

    // ---- O += P @ V_hi: V-frags via tr_read, read ONCE, shared across nf
    const unsigned short* trb = Khi + lane * 4;
    union VU { bf16x8 v; uint2v u2[2]; } vh[8];
#pragma unroll
    for (int vf = 0; vf < 8; ++vf) {
      vh[vf].u2[0] = tr_read(trb + vf * 512);
      vh[vf].u2[1] = tr_read(trb + vf * 512 + 256);
    }
    asm volatile("s_waitcnt lgkmcnt(0)" ::: "memory");
    __builtin_amdgcn_sched_barrier(0);
#pragma unroll
    for (int vf = 0; vf < 8; ++vf) {
      o[0][vf] = mfma16(pah[0].v, vh[vf].v, o[0][vf]);
      o[1][vf] = mfma16(pah[1].v, vh[vf].v, o[1][vf]);
    }
    // explicit drain of this wave's GLD16s (K[t+1]) + LDS ops before barrier
    asm volatile("s_waitcnt vmcnt(0) lgkmcnt(0)" ::: "memory");
    __syncthreads();   // K[t+1] visible to all; WAR turnover on buf[t&1]
  }

  // ---- epilogue: divide by row sums, stage O in LDS (stride 132), write
  float rinv0 = 1.0f / l_run[0];
  float rinv1 = 1.0f / l_run[1];
  f32x4 r40, r41;
#pragma unroll
  for (int r = 0; r < 4; ++r) {
    r40[r] = bperm_f(4 * l4 + r, rinv0);
    r41[r] = bperm_f(4 * l4 + r, rinv1);
  }
  float* wb = (float*)SM;                       // [64][132] f32 (33.8 KB)
#pragma unroll
  for (int vf = 0; vf < 8; ++vf)
#pragma unroll
    for (int r = 0; r < 4; ++r) {
      int c = vf * 16 + l15;
      wb[(w * 32 + 4 * l4 + r) * 132 + c]      = o[0][vf][r] * r40[r];
      wb[(w * 32 + 16 + 4 * l4 + r) * 132 + c] = o[1][vf][r] * r41[r];
    }
  __syncthreads();
#pragma unroll
  for (int p = 0; p < 8; ++p) {
    int row = p * 8 + (tid >> 4);
    int col = (tid & 15) * 8;
    f32x4 v0 = *(const f32x4*)(wb + row * 132 + col);
    f32x4 v1 = *(const f32x4*)(wb + row * 132 + col + 4);
    size_t mg = (size_t)bb * 512 + q0 + row;
    float* op = out + mg * 512 + hd * 128 + col;
    *(f32x4*)op = v0;
    *(f32x4*)(op + 4) = v1;
  }
}

// ---------------------------------------------------------------------------
// Kernel 6: LayerNorm (over C=512) + exact-erf GELU, in place on d_out.
// ---------------------------------------------------------------------------
__global__ __launch_bounds__(256) void ln_gelu_kernel(
    float* __restrict__ io, const float* __restrict__ gamma,
    const float* __restrict__ beta) {
  int w = threadIdx.x >> 6, lane = threadIdx.x & 63;
  size_t row = (size_t)blockIdx.x * 4 + w;
  float* p = io + row * 512;
  f32x4 x0 = *(const f32x4*)(p + lane * 8);
  f32x4 x1 = *(const f32x4*)(p + lane * 8 + 4);
  float s = x0[0] + x0[1] + x0[2] + x0[3] + x1[0] + x1[1] + x1[2] + x1[3];
#pragma unroll
  for (int off = 32; off >= 1; off >>= 1) s += __shfl_xor(s, off);
  float mu = s * (1.0f / 512.0f);
  float vs = 0.f;
#pragma unroll
  for (int e = 0; e < 4; ++e) {
    float d0 = x0[e] - mu; vs += d0 * d0;
    float d1 = x1[e] - mu; vs += d1 * d1;
  }
#pragma unroll
  for (int off = 32; off >= 1; off >>= 1) vs += __shfl_xor(vs, off);
  float rs = rsqrtf(vs * (1.0f / 512.0f) + 1e-5f);
  f32x4 g0 = *(const f32x4*)(gamma + lane * 8);
  f32x4 g1 = *(const f32x4*)(gamma + lane * 8 + 4);
  f32x4 b0 = *(const f32x4*)(beta + lane * 8);
  f32x4 b1 = *(const f32x4*)(beta + lane * 8 + 4);
  f32x4 y0, y1;
#pragma unroll
  for (int e = 0; e < 4; ++e) {
    float y = (x0[e] - mu) * rs * g0[e] + b0[e];
    y0[e] = 0.5f * y * (1.0f + erff(y * 0.70710678118654752f));
    float z = (x1[e] - mu) * rs * g1[e] + b1[e];
    y1[e] = 0.5f * z * (1.0f + erff(z * 0.70710678118654752f));
  }
  *(f32x4*)(p + lane * 8) = y0;
  *(f32x4*)(p + lane * 8 + 4) = y1;
}

// ---------------------------------------------------------------------------
// Host launcher.  Inputs: [0]=t [1]=h [2]=W [3]=b [4]=adj [5]=gamma [6]=beta
// Workspace (~129 MB):
//   h_hi   = ws + 0          (16.7M u16)  -- dead after proj; reused for adj_bf
//   h_lo   = ws + 16777216
//   hp_hi  = ws + 33554432
//   hp_lo  = ws + 50331648
//   Wt_hi  = ws + 67108864   (262144 u16)
//   Wt_lo  = ws + 67371008
//   adj_bf = ws + 0          (262144 u16, written after proj_gemm)
// ---------------------------------------------------------------------------
extern "C" void kernel_launch(void* const* d_in, const int* in_sizes, int n_in,
                              void* d_out, int out_size, void* d_ws, size_t ws_size,
                              hipStream_t stream) {
  const float* h     = (const float*)d_in[1];
  const float* W     = (const float*)d_in[2];
  const float* bias  = (const float*)d_in[3];
  const float* adj   = (const float*)d_in[4];
  const float* gamma = (const float*)d_in[5];
  const float* beta  = (const float*)d_in[6];
  float* out = (float*)d_out;

  unsigned short* ws = (unsigned short*)d_ws;
  unsigned short* h_hi   = ws;
  unsigned short* h_lo   = ws + 16777216;
  unsigned short* hp_hi  = ws + 33554432;
  unsigned short* hp_lo  = ws + 50331648;
  unsigned short* Wt_hi  = ws + 67108864;
  unsigned short* Wt_lo  = ws + 67371008;
  unsigned short* adj_bf = ws;                  // reuse dead h_hi region

  cast_split_h<<<8192, 256, 0, stream>>>(h, h_hi, h_lo);
  cast_split_Wt<<<1024, 256, 0, stream>>>(W, Wt_hi, Wt_lo);
  proj_gemm<<<1024, 256, 0, stream>>>(h_hi, h_lo, Wt_hi, Wt_lo, bias, hp_hi, hp_lo);
  cast_adj<<<128, 256, 0, stream>>>(adj, adj_bf);   // after proj (h_hi dead)
  attn_kernel<<<2048, 128, 0, stream>>>(hp_hi, hp_lo, adj_bf, out);
  ln_gelu_kernel<<<8192, 256, 0, stream>>>(out, gamma, beta);
}

// Round 14
// 216.029 us; speedup vs baseline: 1.0744x; 1.0744x over previous
//
#include <hip/hip_runtime.h>
#include <stdint.h>

// ---------------------------------------------------------------------------
// GraphAttentionLayer fused pipeline, MI355X (gfx950)
// B=64 S=512 C=512 H=4 D=128.  Split-bf16 (hi+lo) 3-term MFMA for GEMM/QK^T.
// Round 14: attn reverted to round-12 (2-wave experiment regressed: occupancy
// dominates over LDS traffic).  proj_gemm double-buffered (1 barrier/K-step,
// hardened drains — the pattern proven in attn r7-r12).  attn output + LN
// input in bf16 (saves 64MB HBM); LN math still fp32.
// ---------------------------------------------------------------------------

typedef float  f32x4   __attribute__((ext_vector_type(4)));
typedef short  bf16x8  __attribute__((ext_vector_type(8)));
typedef unsigned short ushort8 __attribute__((ext_vector_type(8)));
typedef unsigned int   uint2v  __attribute__((ext_vector_type(2)));

#define GLD16(src, dst)                                                        \
  __builtin_amdgcn_global_load_lds(                                            \
      (const __attribute__((address_space(1))) void*)(src),                    \
      (__attribute__((address_space(3))) void*)(dst), 16, 0, 0)

__device__ __forceinline__ unsigned short f32_to_bf16(float x) {
  union { float f; unsigned int u; } v; v.f = x;
  unsigned int r = v.u + 0x7FFFu + ((v.u >> 16) & 1u);
  return (unsigned short)(r >> 16);
}
__device__ __forceinline__ float bf16_to_f32(unsigned int h) {
  union { float f; unsigned int u; } v; v.u = h << 16;
  return v.f;
}
__device__ __forceinline__ f32x4 mfma16(bf16x8 a, bf16x8 b, f32x4 c) {
  return __builtin_amdgcn_mfma_f32_16x16x32_bf16(a, b, c, 0, 0, 0);
}
__device__ __forceinline__ float bperm_f(int srcLane, float v) {
  return __int_as_float(__builtin_amdgcn_ds_bpermute(srcLane << 2, __float_as_int(v)));
}
// HW transpose read, canonical per-lane b64 address (base + lane*8B).
__device__ __forceinline__ uint2v tr_read(const unsigned short* p) {
  uint2v r;
  asm volatile("ds_read_b64_tr_b16 %0, %1"
               : "=v"(r)
               : "v"((const __attribute__((address_space(3))) void*)p)
               : "memory");
  return r;
}

// ---------------------------------------------------------------------------
// Kernel 1: split h (fp32) -> h_hi, h_lo (bf16).  8 elems/thread.
// ---------------------------------------------------------------------------
__global__ __launch_bounds__(256) void cast_split_h(
    const float* __restrict__ src, unsigned short* __restrict__ dhi,
    unsigned short* __restrict__ dlo) {
  size_t i = ((size_t)blockIdx.x * 256 + threadIdx.x) * 8;
  f32x4 a = *(const f32x4*)(src + i);
  f32x4 b = *(const f32x4*)(src + i + 4);
  ushort8 hi, lo;
#pragma unroll
  for (int e = 0; e < 4; ++e) {
    unsigned short h0 = f32_to_bf16(a[e]);
    hi[e] = h0; lo[e] = f32_to_bf16(a[e] - bf16_to_f32(h0));
    unsigned short h1 = f32_to_bf16(b[e]);
    hi[4 + e] = h1; lo[4 + e] = f32_to_bf16(b[e] - bf16_to_f32(h1));
  }
  *(ushort8*)(dhi + i) = hi;
  *(ushort8*)(dlo + i) = lo;
}

// ---------------------------------------------------------------------------
// Kernel 2: W [H,C,D] fp32 -> Wt_hi/lo [H,D,C] bf16 (transposed per head).
// ---------------------------------------------------------------------------
__global__ __launch_bounds__(256) void cast_split_Wt(
    const float* __restrict__ W, unsigned short* __restrict__ whi,
    unsigned short* __restrict__ wlo) {
  int o = blockIdx.x * 256 + threadIdx.x;      // [0, 4*128*512)
  int hd = o >> 16;                             // head
  int rem = o & 65535;
  int d = rem >> 9;                             // [0,128)
  int c = rem & 511;                            // [0,512)
  float v = W[((size_t)(hd * 512 + c)) * 128 + d];
  unsigned short h0 = f32_to_bf16(v);
  whi[o] = h0;
  wlo[o] = f32_to_bf16(v - bf16_to_f32(h0));
}

// ---------------------------------------------------------------------------
// Kernel 2b: adj (fp32) -> bf16 (exact for 0/1 masks).  8 elems/thread.
// ---------------------------------------------------------------------------
__global__ __launch_bounds__(256) void cast_adj(
    const float* __restrict__ src, unsigned short* __restrict__ dst) {
  size_t i = ((size_t)blockIdx.x * 256 + threadIdx.x) * 8;
  f32x4 a = *(const f32x4*)(src + i);
  f32x4 b = *(const f32x4*)(src + i + 4);
  ushort8 o;
#pragma unroll
  for (int e = 0; e < 4; ++e) {
    o[e] = f32_to_bf16(a[e]);
    o[4 + e] = f32_to_bf16(b[e]);
  }
  *(ushort8*)(dst + i) = o;
}

// ---------------------------------------------------------------------------
// Kernel 3: projection GEMM  hp = h @ Wall + bias   ([32768x512]@[512x512])
// split-bf16 3-term.  128x128 tile, BK=32, 4 waves (2x2), 16x16x32 MFMA.
// Round 14: DOUBLE-BUFFERED staging — stage ks+1 while computing ks, ONE
// barrier per K-step with explicit vmcnt/lgkm drain (attn-r12-proven sync).
// LDS 64KB (2 x {Ah,Al,Bh,Bl}).  Epilogue stages through buf0, coalesced.
// ---------------------------------------------------------------------------
__global__ __launch_bounds__(256, 2) void proj_gemm(
    const unsigned short* __restrict__ ahi, const unsigned short* __restrict__ alo,
    const unsigned short* __restrict__ whi, const unsigned short* __restrict__ wlo,
    const float* __restrict__ bias, unsigned short* __restrict__ hp_hi,
    unsigned short* __restrict__ hp_lo) {
  int bid = blockIdx.x;
  int swz = (bid & 7) * 128 + (bid >> 3);       // XCD-contiguous work chunks
  int nt = swz & 3, mt = swz >> 2;
  int m0 = mt * 128, n0 = nt * 128;             // n-tile == head nt

  // 2 buffers x 16384 u16: Ah @+0, Al @+4096, Bh @+8192, Bl @+12288
  __shared__ alignas(16) unsigned short PSM[32768];   // 64 KB

  int tid = threadIdx.x, wv = tid >> 6, lane = tid & 63;
  int l15 = lane & 15, l4 = lane >> 4;
  int wr = wv >> 1, wc = wv & 1;

  f32x4 acc[4][4];
#pragma unroll
  for (int a = 0; a < 4; ++a)
#pragma unroll
    for (int b = 0; b < 4; ++b) acc[a][b] = (f32x4){0.f, 0.f, 0.f, 0.f};

  // ---- prologue: stage ks=0 into buf0
  for (int i = wv; i < 32; i += 4) {
    int grp = i >> 3, j = i & 7;
    int row = j * 16 + (lane >> 2);
    int off = (lane & 3) * 16;
    int sw = ((row >> 1) & 3) << 4;
    const unsigned short* sb = (grp == 0) ? ahi : (grp == 1) ? alo
                             : (grp == 2) ? whi : wlo;
    size_t srcoff = (grp < 2) ? ((size_t)(m0 + row) * 512) * 2
                              : ((size_t)(nt * 128 + row) * 512) * 2;
    GLD16((const char*)sb + srcoff + (off ^ sw), PSM + grp * 4096 + j * 512);
  }
  asm volatile("s_waitcnt vmcnt(0)" ::: "memory");
  __syncthreads();

  for (int ks = 0; ks < 16; ++ks) {
    const unsigned short* base = PSM + (ks & 1) * 16384;
    // ---- stage ks+1 into the other buffer (overlaps compute)
    if (ks < 15) {
      unsigned short* nb = PSM + ((ks + 1) & 1) * 16384;
      int k1 = (ks + 1) * 32;
      for (int i = wv; i < 32; i += 4) {
        int grp = i >> 3, j = i & 7;
        int row = j * 16 + (lane >> 2);
        int off = (lane & 3) * 16;
        int sw = ((row >> 1) & 3) << 4;
        const unsigned short* sb = (grp == 0) ? ahi : (grp == 1) ? alo
                                 : (grp == 2) ? whi : wlo;
        size_t srcoff = (grp < 2) ? ((size_t)(m0 + row) * 512 + k1) * 2
                                  : ((size_t)(nt * 128 + row) * 512 + k1) * 2;
        GLD16((const char*)sb + srcoff + (off ^ sw), nb + grp * 4096 + j * 512);
      }
    }

    const unsigned short* Ah = base;
    const unsigned short* Al = base + 4096;
    const unsigned short* Bh = base + 8192;
    const unsigned short* Bl = base + 12288;
    bf16x8 fah[4], fal[4], fbh[4], fbl[4];
#pragma unroll
    for (int f = 0; f < 4; ++f) {
      int mr = wr * 64 + f * 16 + l15;
      int aadr = mr * 64 + ((16 * l4) ^ (((mr >> 1) & 3) << 4));
      fah[f] = *(const bf16x8*)((const char*)Ah + aadr);
      fal[f] = *(const bf16x8*)((const char*)Al + aadr);
      int nr = wc * 64 + f * 16 + l15;
      int badr = nr * 64 + ((16 * l4) ^ (((nr >> 1) & 3) << 4));
      fbh[f] = *(const bf16x8*)((const char*)Bh + badr);
      fbl[f] = *(const bf16x8*)((const char*)Bl + badr);
    }
#pragma unroll
    for (int a = 0; a < 4; ++a)
#pragma unroll
      for (int b = 0; b < 4; ++b) {
        acc[a][b] = mfma16(fah[a], fbh[b], acc[a][b]);
        acc[a][b] = mfma16(fah[a], fbl[b], acc[a][b]);
        acc[a][b] = mfma16(fal[a], fbh[b], acc[a][b]);
      }
    // drain this wave's GLD16s (ks+1) + LDS reads, then barrier
    asm volatile("s_waitcnt vmcnt(0) lgkmcnt(0)" ::: "memory");
    __syncthreads();
  }

  // epilogue: +bias, RNE split, LDS-staged (buf0 Ah/Al) coalesced writes.
  unsigned short* Eh = PSM;
  unsigned short* El = PSM + 4096;
#pragma unroll
  for (int a = 0; a < 4; ++a) {
    __syncthreads();
#pragma unroll
    for (int b = 0; b < 4; ++b) {
      int cloc = wc * 64 + b * 16 + l15;
      float bv = bias[n0 + cloc];
#pragma unroll
      for (int r = 0; r < 4; ++r) {
        int rloc = wr * 16 + 4 * l4 + r;
        float v = acc[a][b][r] + bv;
        unsigned short hh = f32_to_bf16(v);
        Eh[rloc * 128 + cloc] = hh;
        El[rloc * 128 + cloc] = f32_to_bf16(v - bf16_to_f32(hh));
      }
    }
    __syncthreads();
    int rr = tid >> 3, c16 = (tid & 7) * 16;
    int mg = m0 + (rr >> 4) * 64 + a * 16 + (rr & 15);
    bf16x8 vh0 = *(const bf16x8*)(Eh + rr * 128 + c16);
    bf16x8 vh1 = *(const bf16x8*)(Eh + rr * 128 + c16 + 8);
    bf16x8 vl0 = *(const bf16x8*)(El + rr * 128 + c16);
    bf16x8 vl1 = *(const bf16x8*)(El + rr * 128 + c16 + 8);
    *(bf16x8*)(hp_hi + (size_t)mg * 512 + n0 + c16) = vh0;
    *(bf16x8*)(hp_hi + (size_t)mg * 512 + n0 + c16 + 8) = vh1;
    *(bf16x8*)(hp_lo + (size_t)mg * 512 + n0 + c16) = vl0;
    *(bf16x8*)(hp_lo + (size_t)mg * 512 + n0 + c16 + 8) = vl1;
  }
}

// ---------------------------------------------------------------------------
// Kernel 5: flash attention (round-12 version; output now bf16).
// Block = (b, head, q-tile of 64), 4 waves x 16 q.  K subtiled
// [8 sd][32 kv][16 d], double-buffered.  QK^T b128 frags; PV via tr_read
// (canonical per-lane addr).  PV single-term trunc-bf16(P) @ V_hi.  One
// barrier per tile, explicit drains.  48KB pad -> 3 blocks/CU.  bf16 adj.
// ---------------------------------------------------------------------------
__global__ __launch_bounds__(256, 3) void attn_kernel(
    const unsigned short* __restrict__ hp_hi, const unsigned short* __restrict__ hp_lo,
    const unsigned short* __restrict__ adjb, unsigned short* __restrict__ ob) {
  int bid = blockIdx.x;
  int swz = (bid & 7) * 256 + (bid >> 3);       // 8 q-tiles of one (b,h) per XCD
  int qt = swz & 7;
  int hd = (swz >> 3) & 3;
  int bb = swz >> 5;
  int q0 = qt * 64;

  __shared__ alignas(16) unsigned short SM[24576];     // 48 KB -> 3 blocks/CU
  // buf0: K_hi @0, K_lo @4096 ; buf1: K_hi @8192, K_lo @12288  (u16 offsets)

  int tid = threadIdx.x, w = tid >> 6, lane = tid & 63;
  int l15 = lane & 15, l4 = lane >> 4;
  int qg = q0 + w * 16 + l15;                   // this lane's softmax q row

  bf16x8 qh[4], ql[4];
  {
    size_t base = ((size_t)bb * 512 + qg) * 512 + hd * 128 + 8 * l4;
#pragma unroll
    for (int ds = 0; ds < 4; ++ds) {
      qh[ds] = *(const bf16x8*)(hp_hi + base + ds * 32);
      ql[ds] = *(const bf16x8*)(hp_lo + base + ds * 32);
    }
  }

  f32x4 o[8];
#pragma unroll
  for (int vf = 0; vf < 8; ++vf) o[vf] = (f32x4){0.f, 0.f, 0.f, 0.f};
  float m_run = -3.0e38f, l_run = 0.f;

  const unsigned short* ssb = (w & 2) ? hp_lo : hp_hi;
  int sdst = (w & 2) ? 4096 : 0;
  int sdbase = (w & 1) * 4;
  int skv = lane >> 1, sdh = lane & 1;

  {
    size_t rowb = ((size_t)(bb * 512 + skv)) * 1024 + hd * 256 + sdh * 16;
#pragma unroll
    for (int s2 = 0; s2 < 4; ++s2) {
      int sd = sdbase + s2;
      GLD16((const char*)ssb + rowb + sd * 32, SM + sdst + sd * 512);
    }
  }
  asm volatile("s_waitcnt vmcnt(0)" ::: "memory");
  __syncthreads();

  for (int t = 0; t < 16; ++t) {
    int kv0 = t * 32;
    const unsigned short* Kb = SM + ((t & 1) << 13);
    const unsigned short* Khi = Kb;
    const unsigned short* Klo = Kb + 4096;

    if (t < 15) {
      unsigned short* Nb = SM + (((t + 1) & 1) << 13) + sdst;
      size_t rowb = ((size_t)(bb * 512 + kv0 + 32 + skv)) * 1024 + hd * 256 + sdh * 16;
#pragma unroll
      for (int s2 = 0; s2 < 4; ++s2) {
        int sd = sdbase + s2;
        GLD16((const char*)ssb + rowb + sd * 32, Nb + sd * 512);
      }
    }
    uint2 ua0 = *(const uint2*)(adjb + (size_t)qg * 512 + kv0 + 4 * l4);
    uint2 ua1 = *(const uint2*)(adjb + (size_t)qg * 512 + kv0 + 16 + 4 * l4);
    f32x4 av0, av1;
    av0[0] = bf16_to_f32(ua0.x & 0xFFFFu); av0[1] = bf16_to_f32(ua0.x >> 16);
    av0[2] = bf16_to_f32(ua0.y & 0xFFFFu); av0[3] = bf16_to_f32(ua0.y >> 16);
    av1[0] = bf16_to_f32(ua1.x & 0xFFFFu); av1[1] = bf16_to_f32(ua1.x >> 16);
    av1[2] = bf16_to_f32(ua1.y & 0xFFFFu); av1[3] = bf16_to_f32(ua1.y >> 16);

    f32x4 sc0 = {0.f, 0.f, 0.f, 0.f}, sc1 = {0.f, 0.f, 0.f, 0.f};
#pragma unroll
    for (int ds = 0; ds < 4; ++ds) {
      int boff = (2 * ds + (l4 >> 1)) * 1024 + 16 * (l4 & 1);
      int a0 = boff + l15 * 32;
      int a1 = boff + (16 + l15) * 32;
      bf16x8 kh0 = *(const bf16x8*)((const char*)Khi + a0);
      bf16x8 kl0 = *(const bf16x8*)((const char*)Klo + a0);
      bf16x8 kh1 = *(const bf16x8*)((const char*)Khi + a1);
      bf16x8 kl1 = *(const bf16x8*)((const char*)Klo + a1);
      sc0 = mfma16(kh0, qh[ds], sc0); sc1 = mfma16(kh1, qh[ds], sc1);
      sc0 = mfma16(kh0, ql[ds], sc0); sc1 = mfma16(kh1, ql[ds], sc1);
      sc0 = mfma16(kl0, qh[ds], sc0); sc1 = mfma16(kl1, qh[ds], sc1);
    }

    float p0[4], p1[4];
    float tm = -3.0e38f;
#pragma unroll
    for (int r = 0; r < 4; ++r) {
      p0[r] = sc0[r] * av0[r];
      p1[r] = sc1[r] * av1[r];
      tm = fmaxf(tm, fmaxf(p0[r], p1[r]));
    }
    tm = fmaxf(tm, __shfl_xor(tm, 16));
    tm = fmaxf(tm, __shfl_xor(tm, 32));
    if (__any(tm > m_run + 8.0f)) {             // T13 defer-rescale
      float mn = fmaxf(m_run, tm);
      float scl = __expf(m_run - mn);
      m_run = mn;
      l_run *= scl;
      f32x4 s4;
#pragma unroll
      for (int r = 0; r < 4; ++r) s4[r] = bperm_f(4 * l4 + r, scl);
#pragma unroll
      for (int vf = 0; vf < 8; ++vf)
#pragma unroll
        for (int r = 0; r < 4; ++r) o[vf][r] *= s4[r];
    }
    float ps = 0.f;
#pragma unroll
    for (int r = 0; r < 4; ++r) {
      p0[r] = __expf(p0[r] - m_run); ps += p0[r];
      p1[r] = __expf(p1[r] - m_run); ps += p1[r];
    }
    ps += __shfl_xor(ps, 16);
    ps += __shfl_xor(ps, 32);
    l_run += ps;

    union PU { bf16x8 v; unsigned u[4]; } pah;
#pragma unroll
    for (int i = 0; i < 4; ++i) {
      float fa = (i < 2) ? p0[2 * i] : p1[2 * (i - 2)];
      float fb = (i < 2) ? p0[2 * i + 1] : p1[2 * (i - 2) + 1];
      pah.u[i] = (__float_as_uint(fa) >> 16) |
                 (__float_as_uint(fb) & 0xFFFF0000u);
    }

    const unsigned short* trb = Khi + lane * 4;
    union VU { bf16x8 v; uint2v u2[2]; } vh[8];
#pragma unroll
    for (int vf = 0; vf < 8; ++vf) {
      vh[vf].u2[0] = tr_read(trb + vf * 512);
      vh[vf].u2[1] = tr_read(trb + vf * 512 + 256);
    }
    asm volatile("s_waitcnt lgkmcnt(0)" ::: "memory");
    __builtin_amdgcn_sched_barrier(0);
#pragma unroll
    for (int vf = 0; vf < 8; ++vf)
      o[vf] = mfma16(pah.v, vh[vf].v, o[vf]);
    asm volatile("s_waitcnt vmcnt(0) lgkmcnt(0)" ::: "memory");
    __syncthreads();
  }

  // ---- epilogue: divide by row sums, stage in LDS, coalesced bf16 writes
  float rinv = 1.0f / l_run;
  f32x4 r4;
#pragma unroll
  for (int r = 0; r < 4; ++r) r4[r] = bperm_f(4 * l4 + r, rinv);
  float* wbase = (float*)SM + w * 2048;         // [16][128] f32 per wave
#pragma unroll
  for (int vf = 0; vf < 8; ++vf)
#pragma unroll
    for (int r = 0; r < 4; ++r)
      wbase[(4 * l4 + r) * 128 + vf * 16 + l15] = o[vf][r] * r4[r];
  __syncthreads();
#pragma unroll
  for (int p = 0; p < 4; ++p) {
    int row = p * 4 + l4;
    f32x4 v0 = *(const f32x4*)(wbase + row * 128 + l15 * 8);
    f32x4 v1 = *(const f32x4*)(wbase + row * 128 + l15 * 8 + 4);
    ushort8 o8;
#pragma unroll
    for (int e = 0; e < 4; ++e) {
      o8[e] = f32_to_bf16(v0[e]);
      o8[4 + e] = f32_to_bf16(v1[e]);
    }
    size_t mg = (size_t)bb * 512 + q0 + w * 16 + row;
    *(ushort8*)(ob + mg * 512 + hd * 128 + l15 * 8) = o8;
  }
}

// ---------------------------------------------------------------------------
// Kernel 6: LayerNorm (over C=512) + exact-erf GELU.  Reads bf16 attn
// output, computes in fp32, writes fp32 d_out.  One wave per row.
// ---------------------------------------------------------------------------
__global__ __launch_bounds__(256) void ln_gelu_kernel(
    const unsigned short* __restrict__ in, float* __restrict__ outp,
    const float* __restrict__ gamma, const float* __restrict__ beta) {
  int w = threadIdx.x >> 6, lane = threadIdx.x & 63;
  size_t row = (size_t)blockIdx.x * 4 + w;
  ushort8 v = *(const ushort8*)(in + row * 512 + lane * 8);
  float x[8];
#pragma unroll
  for (int e = 0; e < 8; ++e) x[e] = bf16_to_f32((unsigned int)(unsigned short)v[e]);
  float s = 0.f;
#pragma unroll
  for (int e = 0; e < 8; ++e) s += x[e];
#pragma unroll
  for (int off = 32; off >= 1; off >>= 1) s += __shfl_xor(s, off);
  float mu = s * (1.0f / 512.0f);
  float vs = 0.f;
#pragma unroll
  for (int e = 0; e < 8; ++e) {
    float d = x[e] - mu; vs += d * d;
  }
#pragma unroll
  for (int off = 32; off >= 1; off >>= 1) vs += __shfl_xor(vs, off);
  float rs = rsqrtf(vs * (1.0f / 512.0f) + 1e-5f);
  f32x4 g0 = *(const f32x4*)(gamma + lane * 8);
  f32x4 g1 = *(const f32x4*)(gamma + lane * 8 + 4);
  f32x4 b0 = *(const f32x4*)(beta + lane * 8);
  f32x4 b1 = *(const f32x4*)(beta + lane * 8 + 4);
  f32x4 y0, y1;
#pragma unroll
  for (int e = 0; e < 4; ++e) {
    float y = (x[e] - mu) * rs * g0[e] + b0[e];
    y0[e] = 0.5f * y * (1.0f + erff(y * 0.70710678118654752f));
    float z = (x[4 + e] - mu) * rs * g1[e] + b1[e];
    y1[e] = 0.5f * z * (1.0f + erff(z * 0.70710678118654752f));
  }
  float* p = outp + row * 512 + lane * 8;
  *(f32x4*)p = y0;
  *(f32x4*)(p + 4) = y1;
}

// ---------------------------------------------------------------------------
// Host launcher.  Inputs: [0]=t [1]=h [2]=W [3]=b [4]=adj [5]=gamma [6]=beta
// Workspace (~129 MB):
//   h_hi   = ws + 0          (16.7M u16)  -- dead after proj; reused: adj_bf
//   h_lo   = ws + 16777216                -- dead after proj; reused: ob
//   hp_hi  = ws + 33554432
//   hp_lo  = ws + 50331648
//   Wt_hi  = ws + 67108864   (262144 u16)
//   Wt_lo  = ws + 67371008
// ---------------------------------------------------------------------------
extern "C" void kernel_launch(void* const* d_in, const int* in_sizes, int n_in,
                              void* d_out, int out_size, void* d_ws, size_t ws_size,
                              hipStream_t stream) {
  const float* h     = (const float*)d_in[1];
  const float* W     = (const float*)d_in[2];
  const float* bias  = (const float*)d_in[3];
  const float* adj   = (const float*)d_in[4];
  const float* gamma = (const float*)d_in[5];
  const float* beta  = (const float*)d_in[6];
  float* out = (float*)d_out;

  unsigned short* ws = (unsigned short*)d_ws;
  unsigned short* h_hi   = ws;
  unsigned short* h_lo   = ws + 16777216;
  unsigned short* hp_hi  = ws + 33554432;
  unsigned short* hp_lo  = ws + 50331648;
  unsigned short* Wt_hi  = ws + 67108864;
  unsigned short* Wt_lo  = ws + 67371008;
  unsigned short* adj_bf = ws;                  // reuse dead h_hi region
  unsigned short* ob     = ws + 16777216;       // reuse dead h_lo region

  cast_split_h<<<8192, 256, 0, stream>>>(h, h_hi, h_lo);
  cast_split_Wt<<<1024, 256, 0, stream>>>(W, Wt_hi, Wt_lo);
  proj_gemm<<<1024, 256, 0, stream>>>(h_hi, h_lo, Wt_hi, Wt_lo, bias, hp_hi, hp_lo);
  cast_adj<<<128, 256, 0, stream>>>(adj, adj_bf);   // after proj (h_hi dead)
  attn_kernel<<<2048, 256, 0, stream>>>(hp_hi, hp_lo, adj_bf, ob);
  ln_gelu_kernel<<<8192, 256, 0, stream>>>(ob, out, gamma, beta);
}

// Round 15
// 194.040 us; speedup vs baseline: 1.1962x; 1.1133x over previous
//
#include <hip/hip_runtime.h>
#include <stdint.h>

// ---------------------------------------------------------------------------
// GraphAttentionLayer fused pipeline, MI355X (gfx950)
// B=64 S=512 C=512 H=4 D=128.  Split-bf16 (hi+lo) 3-term MFMA for GEMM/QK^T.
// Round 15: proj reverted to r12 2-barrier structure AND fused with the
// h fp32->bf16 split (A reg-staged from raw f32 h, trunc-split in-register,
// ds_write into the swizzled layout; B stays GLD16).  cast_split_h deleted
// (-128MB HBM round-trip).  attn/ln unchanged from r14 (bf16 intermediate).
// ---------------------------------------------------------------------------

typedef float  f32x4   __attribute__((ext_vector_type(4)));
typedef short  bf16x8  __attribute__((ext_vector_type(8)));
typedef unsigned short ushort8 __attribute__((ext_vector_type(8)));
typedef unsigned int   uint2v  __attribute__((ext_vector_type(2)));

#define GLD16(src, dst)                                                        \
  __builtin_amdgcn_global_load_lds(                                            \
      (const __attribute__((address_space(1))) void*)(src),                    \
      (__attribute__((address_space(3))) void*)(dst), 16, 0, 0)

__device__ __forceinline__ unsigned short f32_to_bf16(float x) {
  union { float f; unsigned int u; } v; v.f = x;
  unsigned int r = v.u + 0x7FFFu + ((v.u >> 16) & 1u);
  return (unsigned short)(r >> 16);
}
__device__ __forceinline__ float bf16_to_f32(unsigned int h) {
  union { float f; unsigned int u; } v; v.u = h << 16;
  return v.f;
}
__device__ __forceinline__ f32x4 mfma16(bf16x8 a, bf16x8 b, f32x4 c) {
  return __builtin_amdgcn_mfma_f32_16x16x32_bf16(a, b, c, 0, 0, 0);
}
__device__ __forceinline__ float bperm_f(int srcLane, float v) {
  return __int_as_float(__builtin_amdgcn_ds_bpermute(srcLane << 2, __float_as_int(v)));
}
// HW transpose read, canonical per-lane b64 address (base + lane*8B).
__device__ __forceinline__ uint2v tr_read(const unsigned short* p) {
  uint2v r;
  asm volatile("ds_read_b64_tr_b16 %0, %1"
               : "=v"(r)
               : "v"((const __attribute__((address_space(3))) void*)p)
               : "memory");
  return r;
}

// ---------------------------------------------------------------------------
// Kernel 2: W [H,C,D] fp32 -> Wt_hi/lo [H,D,C] bf16 (transposed per head).
// ---------------------------------------------------------------------------
__global__ __launch_bounds__(256) void cast_split_Wt(
    const float* __restrict__ W, unsigned short* __restrict__ whi,
    unsigned short* __restrict__ wlo) {
  int o = blockIdx.x * 256 + threadIdx.x;      // [0, 4*128*512)
  int hd = o >> 16;                             // head
  int rem = o & 65535;
  int d = rem >> 9;                             // [0,128)
  int c = rem & 511;                            // [0,512)
  float v = W[((size_t)(hd * 512 + c)) * 128 + d];
  unsigned short h0 = f32_to_bf16(v);
  whi[o] = h0;
  wlo[o] = f32_to_bf16(v - bf16_to_f32(h0));
}

// ---------------------------------------------------------------------------
// Kernel 2b: adj (fp32) -> bf16 (exact for 0/1 masks).  8 elems/thread.
// ---------------------------------------------------------------------------
__global__ __launch_bounds__(256) void cast_adj(
    const float* __restrict__ src, unsigned short* __restrict__ dst) {
  size_t i = ((size_t)blockIdx.x * 256 + threadIdx.x) * 8;
  f32x4 a = *(const f32x4*)(src + i);
  f32x4 b = *(const f32x4*)(src + i + 4);
  ushort8 o;
#pragma unroll
  for (int e = 0; e < 4; ++e) {
    o[e] = f32_to_bf16(a[e]);
    o[4 + e] = f32_to_bf16(b[e]);
  }
  *(ushort8*)(dst + i) = o;
}

// ---------------------------------------------------------------------------
// Kernel 3: FUSED cast+projection GEMM  hp = split(h) @ Wall + bias
// ([32768x512]@[512x512]).  r12 2-barrier structure.  A: reg-staged from f32
// h, trunc-split to hi/lo, ds_write_b64 into swizzled [128][32] tiles.
// B: GLD16 from pre-split Wt.  128x128 tile, BK=32, 4 waves, 16x16x32 MFMA.
// Epilogue: stage through Ah/Al, coalesced bf16x8 writes of hp rows.
// ---------------------------------------------------------------------------
__global__ __launch_bounds__(256, 2) void proj_gemm(
    const float* __restrict__ hsrc,
    const unsigned short* __restrict__ whi, const unsigned short* __restrict__ wlo,
    const float* __restrict__ bias, unsigned short* __restrict__ hp_hi,
    unsigned short* __restrict__ hp_lo) {
  int bid = blockIdx.x;
  int swz = (bid & 7) * 128 + (bid >> 3);       // XCD-contiguous work chunks
  int nt = swz & 3, mt = swz >> 2;
  int m0 = mt * 128, n0 = nt * 128;             // n-tile == head nt

  __shared__ alignas(16) unsigned short Ah[4096], Al[4096], Bh[4096], Bl[4096];

  int tid = threadIdx.x, wv = tid >> 6, lane = tid & 63;
  int l15 = lane & 15, l4 = lane >> 4;
  int wr = wv >> 1, wc = wv & 1;
  int arow = tid >> 3;                          // A-stage: 0..31 (+j*32)
  int acol = (tid & 7) * 4;                     // A-stage f32 col

  f32x4 acc[4][4];
#pragma unroll
  for (int a = 0; a < 4; ++a)
#pragma unroll
    for (int b = 0; b < 4; ++b) acc[a][b] = (f32x4){0.f, 0.f, 0.f, 0.f};

  for (int ks = 0; ks < 16; ++ks) {
    int k0 = ks * 32;
    // ---- B staging via GLD16 (16 chunks over 4 waves)
    for (int i = wv; i < 16; i += 4) {
      int grp = i >> 3, j = i & 7;
      int row = j * 16 + (lane >> 2);
      int off = (lane & 3) * 16;
      int sw = ((row >> 1) & 3) << 4;
      const unsigned short* sb = grp ? wlo : whi;
      unsigned short* db = grp ? Bl : Bh;
      GLD16((const char*)sb + ((size_t)(nt * 128 + row) * 512 + k0) * 2 + (off ^ sw),
            db + j * 512);
    }
    // ---- A staging: f32 loads, trunc-split, swizzled ds_write_b64
#pragma unroll
    for (int j = 0; j < 4; ++j) {
      int r = j * 32 + arow;
      f32x4 x = *(const f32x4*)(hsrc + (size_t)(m0 + r) * 512 + k0 + acol);
      unsigned ua = __float_as_uint(x[0]), ub = __float_as_uint(x[1]);
      unsigned uc = __float_as_uint(x[2]), ud = __float_as_uint(x[3]);
      uint2 ph, pl;
      ph.x = (ua >> 16) | (ub & 0xFFFF0000u);
      ph.y = (uc >> 16) | (ud & 0xFFFF0000u);
      float ra = x[0] - __uint_as_float(ua & 0xFFFF0000u);
      float rb = x[1] - __uint_as_float(ub & 0xFFFF0000u);
      float rc = x[2] - __uint_as_float(uc & 0xFFFF0000u);
      float rd = x[3] - __uint_as_float(ud & 0xFFFF0000u);
      pl.x = (__float_as_uint(ra) >> 16) | (__float_as_uint(rb) & 0xFFFF0000u);
      pl.y = (__float_as_uint(rc) >> 16) | (__float_as_uint(rd) & 0xFFFF0000u);
      int boff = r * 64 + ((acol * 2) ^ (((r >> 1) & 3) << 4));
      *(uint2*)((char*)Ah + boff) = ph;
      *(uint2*)((char*)Al + boff) = pl;
    }
    __syncthreads();   // drains ds_writes (lgkm) + GLD16s (vm)

    bf16x8 fah[4], fal[4], fbh[4], fbl[4];
#pragma unroll
    for (int f = 0; f < 4; ++f) {
      int mr = wr * 64 + f * 16 + l15;
      int aadr = mr * 64 + ((16 * l4) ^ (((mr >> 1) & 3) << 4));
      fah[f] = *(const bf16x8*)((const char*)Ah + aadr);
      fal[f] = *(const bf16x8*)((const char*)Al + aadr);
      int nr = wc * 64 + f * 16 + l15;
      int badr = nr * 64 + ((16 * l4) ^ (((nr >> 1) & 3) << 4));
      fbh[f] = *(const bf16x8*)((const char*)Bh + badr);
      fbl[f] = *(const bf16x8*)((const char*)Bl + badr);
    }
#pragma unroll
    for (int a = 0; a < 4; ++a)
#pragma unroll
      for (int b = 0; b < 4; ++b) {
        acc[a][b] = mfma16(fah[a], fbh[b], acc[a][b]);
        acc[a][b] = mfma16(fah[a], fbl[b], acc[a][b]);
        acc[a][b] = mfma16(fal[a], fbh[b], acc[a][b]);
      }
    __syncthreads();
  }

  // epilogue: +bias, RNE split, LDS-staged coalesced writes of hp rows.
#pragma unroll
  for (int a = 0; a < 4; ++a) {
    __syncthreads();
#pragma unroll
    for (int b = 0; b < 4; ++b) {
      int cloc = wc * 64 + b * 16 + l15;
      float bv = bias[n0 + cloc];
#pragma unroll
      for (int r = 0; r < 4; ++r) {
        int rloc = wr * 16 + 4 * l4 + r;
        float v = acc[a][b][r] + bv;
        unsigned short hh = f32_to_bf16(v);
        Ah[rloc * 128 + cloc] = hh;
        Al[rloc * 128 + cloc] = f32_to_bf16(v - bf16_to_f32(hh));
      }
    }
    __syncthreads();
    int rr = tid >> 3, c16 = (tid & 7) * 16;
    int mg = m0 + (rr >> 4) * 64 + a * 16 + (rr & 15);
    bf16x8 vh0 = *(const bf16x8*)(Ah + rr * 128 + c16);
    bf16x8 vh1 = *(const bf16x8*)(Ah + rr * 128 + c16 + 8);
    bf16x8 vl0 = *(const bf16x8*)(Al + rr * 128 + c16);
    bf16x8 vl1 = *(const bf16x8*)(Al + rr * 128 + c16 + 8);
    *(bf16x8*)(hp_hi + (size_t)mg * 512 + n0 + c16) = vh0;
    *(bf16x8*)(hp_hi + (size_t)mg * 512 + n0 + c16 + 8) = vh1;
    *(bf16x8*)(hp_lo + (size_t)mg * 512 + n0 + c16) = vl0;
    *(bf16x8*)(hp_lo + (size_t)mg * 512 + n0 + c16 + 8) = vl1;
  }
}

// ---------------------------------------------------------------------------
// Kernel 5: flash attention (round-12 structure; bf16 output).
// Block = (b, head, q-tile of 64), 4 waves x 16 q.  K subtiled
// [8 sd][32 kv][16 d], double-buffered.  QK^T b128 frags; PV via tr_read
// (canonical per-lane addr).  PV single-term trunc-bf16(P) @ V_hi.  One
// barrier per tile, explicit drains.  48KB pad -> 3 blocks/CU.  bf16 adj.
// ---------------------------------------------------------------------------
__global__ __launch_bounds__(256, 3) void attn_kernel(
    const unsigned short* __restrict__ hp_hi, const unsigned short* __restrict__ hp_lo,
    const unsigned short* __restrict__ adjb, unsigned short* __restrict__ ob) {
  int bid = blockIdx.x;
  int swz = (bid & 7) * 256 + (bid >> 3);       // 8 q-tiles of one (b,h) per XCD
  int qt = swz & 7;
  int hd = (swz >> 3) & 3;
  int bb = swz >> 5;
  int q0 = qt * 64;

  __shared__ alignas(16) unsigned short SM[24576];     // 48 KB -> 3 blocks/CU
  // buf0: K_hi @0, K_lo @4096 ; buf1: K_hi @8192, K_lo @12288  (u16 offsets)

  int tid = threadIdx.x, w = tid >> 6, lane = tid & 63;
  int l15 = lane & 15, l4 = lane >> 4;
  int qg = q0 + w * 16 + l15;                   // this lane's softmax q row

  bf16x8 qh[4], ql[4];
  {
    size_t base = ((size_t)bb * 512 + qg) * 512 + hd * 128 + 8 * l4;
#pragma unroll
    for (int ds = 0; ds < 4; ++ds) {
      qh[ds] = *(const bf16x8*)(hp_hi + base + ds * 32);
      ql[ds] = *(const bf16x8*)(hp_lo + base + ds * 32);
    }
  }

  f32x4 o[8];
#pragma unroll
  for (int vf = 0; vf < 8; ++vf) o[vf] = (f32x4){0.f, 0.f, 0.f, 0.f};
  float m_run = -3.0e38f, l_run = 0.f;

  const unsigned short* ssb = (w & 2) ? hp_lo : hp_hi;
  int sdst = (w & 2) ? 4096 : 0;
  int sdbase = (w & 1) * 4;
  int skv = lane >> 1, sdh = lane & 1;

  {
    size_t rowb = ((size_t)(bb * 512 + skv)) * 1024 + hd * 256 + sdh * 16;
#pragma unroll
    for (int s2 = 0; s2 < 4; ++s2) {
      int sd = sdbase + s2;
      GLD16((const char*)ssb + rowb + sd * 32, SM + sdst + sd * 512);
    }
  }
  asm volatile("s_waitcnt vmcnt(0)" ::: "memory");
  __syncthreads();

  for (int t = 0; t < 16; ++t) {
    int kv0 = t * 32;
    const unsigned short* Kb = SM + ((t & 1) << 13);
    const unsigned short* Khi = Kb;
    const unsigned short* Klo = Kb + 4096;

    if (t < 15) {
      unsigned short* Nb = SM + (((t + 1) & 1) << 13) + sdst;
      size_t rowb = ((size_t)(bb * 512 + kv0 + 32 + skv)) * 1024 + hd * 256 + sdh * 16;
#pragma unroll
      for (int s2 = 0; s2 < 4; ++s2) {
        int sd = sdbase + s2;
        GLD16((const char*)ssb + rowb + sd * 32, Nb + sd * 512);
      }
    }
    uint2 ua0 = *(const uint2*)(adjb + (size_t)qg * 512 + kv0 + 4 * l4);
    uint2 ua1 = *(const uint2*)(adjb + (size_t)qg * 512 + kv0 + 16 + 4 * l4);
    f32x4 av0, av1;
    av0[0] = bf16_to_f32(ua0.x & 0xFFFFu); av0[1] = bf16_to_f32(ua0.x >> 16);
    av0[2] = bf16_to_f32(ua0.y & 0xFFFFu); av0[3] = bf16_to_f32(ua0.y >> 16);
    av1[0] = bf16_to_f32(ua1.x & 0xFFFFu); av1[1] = bf16_to_f32(ua1.x >> 16);
    av1[2] = bf16_to_f32(ua1.y & 0xFFFFu); av1[3] = bf16_to_f32(ua1.y >> 16);

    f32x4 sc0 = {0.f, 0.f, 0.f, 0.f}, sc1 = {0.f, 0.f, 0.f, 0.f};
#pragma unroll
    for (int ds = 0; ds < 4; ++ds) {
      int boff = (2 * ds + (l4 >> 1)) * 1024 + 16 * (l4 & 1);
      int a0 = boff + l15 * 32;
      int a1 = boff + (16 + l15) * 32;
      bf16x8 kh0 = *(const bf16x8*)((const char*)Khi + a0);
      bf16x8 kl0 = *(const bf16x8*)((const char*)Klo + a0);
      bf16x8 kh1 = *(const bf16x8*)((const char*)Khi + a1);
      bf16x8 kl1 = *(const bf16x8*)((const char*)Klo + a1);
      sc0 = mfma16(kh0, qh[ds], sc0); sc1 = mfma16(kh1, qh[ds], sc1);
      sc0 = mfma16(kh0, ql[ds], sc0); sc1 = mfma16(kh1, ql[ds], sc1);
      sc0 = mfma16(kl0, qh[ds], sc0); sc1 = mfma16(kl1, qh[ds], sc1);
    }

    float p0[4], p1[4];
    float tm = -3.0e38f;
#pragma unroll
    for (int r = 0; r < 4; ++r) {
      p0[r] = sc0[r] * av0[r];
      p1[r] = sc1[r] * av1[r];
      tm = fmaxf(tm, fmaxf(p0[r], p1[r]));
    }
    tm = fmaxf(tm, __shfl_xor(tm, 16));
    tm = fmaxf(tm, __shfl_xor(tm, 32));
    if (__any(tm > m_run + 8.0f)) {             // T13 defer-rescale
      float mn = fmaxf(m_run, tm);
      float scl = __expf(m_run - mn);
      m_run = mn;
      l_run *= scl;
      f32x4 s4;
#pragma unroll
      for (int r = 0; r < 4; ++r) s4[r] = bperm_f(4 * l4 + r, scl);
#pragma unroll
      for (int vf = 0; vf < 8; ++vf)
#pragma unroll
        for (int r = 0; r < 4; ++r) o[vf][r] *= s4[r];
    }
    float ps = 0.f;
#pragma unroll
    for (int r = 0; r < 4; ++r) {
      p0[r] = __expf(p0[r] - m_run); ps += p0[r];
      p1[r] = __expf(p1[r] - m_run); ps += p1[r];
    }
    ps += __shfl_xor(ps, 16);
    ps += __shfl_xor(ps, 32);
    l_run += ps;

    union PU { bf16x8 v; unsigned u[4]; } pah;
#pragma unroll
    for (int i = 0; i < 4; ++i) {
      float fa = (i < 2) ? p0[2 * i] : p1[2 * (i - 2)];
      float fb = (i < 2) ? p0[2 * i + 1] : p1[2 * (i - 2) + 1];
      pah.u[i] = (__float_as_uint(fa) >> 16) |
                 (__float_as_uint(fb) & 0xFFFF0000u);
    }

    const unsigned short* trb = Khi + lane * 4;
    union VU { bf16x8 v; uint2v u2[2]; } vh[8];
#pragma unroll
    for (int vf = 0; vf < 8; ++vf) {
      vh[vf].u2[0] = tr_read(trb + vf * 512);
      vh[vf].u2[1] = tr_read(trb + vf * 512 + 256);
    }
    asm volatile("s_waitcnt lgkmcnt(0)" ::: "memory");
    __builtin_amdgcn_sched_barrier(0);
#pragma unroll
    for (int vf = 0; vf < 8; ++vf)
      o[vf] = mfma16(pah.v, vh[vf].v, o[vf]);
    asm volatile("s_waitcnt vmcnt(0) lgkmcnt(0)" ::: "memory");
    __syncthreads();
  }

  // ---- epilogue: divide by row sums, stage in LDS, coalesced bf16 writes
  float rinv = 1.0f / l_run;
  f32x4 r4;
#pragma unroll
  for (int r = 0; r < 4; ++r) r4[r] = bperm_f(4 * l4 + r, rinv);
  float* wbase = (float*)SM + w * 2048;         // [16][128] f32 per wave
#pragma unroll
  for (int vf = 0; vf < 8; ++vf)
#pragma unroll
    for (int r = 0; r < 4; ++r)
      wbase[(4 * l4 + r) * 128 + vf * 16 + l15] = o[vf][r] * r4[r];
  __syncthreads();
#pragma unroll
  for (int p = 0; p < 4; ++p) {
    int row = p * 4 + l4;
    f32x4 v0 = *(const f32x4*)(wbase + row * 128 + l15 * 8);
    f32x4 v1 = *(const f32x4*)(wbase + row * 128 + l15 * 8 + 4);
    ushort8 o8;
#pragma unroll
    for (int e = 0; e < 4; ++e) {
      o8[e] = f32_to_bf16(v0[e]);
      o8[4 + e] = f32_to_bf16(v1[e]);
    }
    size_t mg = (size_t)bb * 512 + q0 + w * 16 + row;
    *(ushort8*)(ob + mg * 512 + hd * 128 + l15 * 8) = o8;
  }
}

// ---------------------------------------------------------------------------
// Kernel 6: LayerNorm (over C=512) + exact-erf GELU.  Reads bf16 attn
// output, computes in fp32, writes fp32 d_out.  One wave per row.
// ---------------------------------------------------------------------------
__global__ __launch_bounds__(256) void ln_gelu_kernel(
    const unsigned short* __restrict__ in, float* __restrict__ outp,
    const float* __restrict__ gamma, const float* __restrict__ beta) {
  int w = threadIdx.x >> 6, lane = threadIdx.x & 63;
  size_t row = (size_t)blockIdx.x * 4 + w;
  ushort8 v = *(const ushort8*)(in + row * 512 + lane * 8);
  float x[8];
#pragma unroll
  for (int e = 0; e < 8; ++e) x[e] = bf16_to_f32((unsigned int)(unsigned short)v[e]);
  float s = 0.f;
#pragma unroll
  for (int e = 0; e < 8; ++e) s += x[e];
#pragma unroll
  for (int off = 32; off >= 1; off >>= 1) s += __shfl_xor(s, off);
  float mu = s * (1.0f / 512.0f);
  float vs = 0.f;
#pragma unroll
  for (int e = 0; e < 8; ++e) {
    float d = x[e] - mu; vs += d * d;
  }
#pragma unroll
  for (int off = 32; off >= 1; off >>= 1) vs += __shfl_xor(vs, off);
  float rs = rsqrtf(vs * (1.0f / 512.0f) + 1e-5f);
  f32x4 g0 = *(const f32x4*)(gamma + lane * 8);
  f32x4 g1 = *(const f32x4*)(gamma + lane * 8 + 4);
  f32x4 b0 = *(const f32x4*)(beta + lane * 8);
  f32x4 b1 = *(const f32x4*)(beta + lane * 8 + 4);
  f32x4 y0, y1;
#pragma unroll
  for (int e = 0; e < 4; ++e) {
    float y = (x[e] - mu) * rs * g0[e] + b0[e];
    y0[e] = 0.5f * y * (1.0f + erff(y * 0.70710678118654752f));
    float z = (x[4 + e] - mu) * rs * g1[e] + b1[e];
    y1[e] = 0.5f * z * (1.0f + erff(z * 0.70710678118654752f));
  }
  float* p = outp + row * 512 + lane * 8;
  *(f32x4*)p = y0;
  *(f32x4*)(p + 4) = y1;
}

// ---------------------------------------------------------------------------
// Host launcher.  Inputs: [0]=t [1]=h [2]=W [3]=b [4]=adj [5]=gamma [6]=beta
// Workspace (~129 MB):
//   adj_bf = ws + 0          (262144 u16)
//   ob     = ws + 16777216   (16.7M u16, bf16 attn out)
//   hp_hi  = ws + 33554432
//   hp_lo  = ws + 50331648
//   Wt_hi  = ws + 67108864   (262144 u16)
//   Wt_lo  = ws + 67371008
// ---------------------------------------------------------------------------
extern "C" void kernel_launch(void* const* d_in, const int* in_sizes, int n_in,
                              void* d_out, int out_size, void* d_ws, size_t ws_size,
                              hipStream_t stream) {
  const float* h     = (const float*)d_in[1];
  const float* W     = (const float*)d_in[2];
  const float* bias  = (const float*)d_in[3];
  const float* adj   = (const float*)d_in[4];
  const float* gamma = (const float*)d_in[5];
  const float* beta  = (const float*)d_in[6];
  float* out = (float*)d_out;

  unsigned short* ws = (unsigned short*)d_ws;
  unsigned short* adj_bf = ws;
  unsigned short* ob     = ws + 16777216;
  unsigned short* hp_hi  = ws + 33554432;
  unsigned short* hp_lo  = ws + 50331648;
  unsigned short* Wt_hi  = ws + 67108864;
  unsigned short* Wt_lo  = ws + 67371008;

  cast_split_Wt<<<1024, 256, 0, stream>>>(W, Wt_hi, Wt_lo);
  cast_adj<<<128, 256, 0, stream>>>(adj, adj_bf);
  proj_gemm<<<1024, 256, 0, stream>>>(h, Wt_hi, Wt_lo, bias, hp_hi, hp_lo);
  attn_kernel<<<2048, 256, 0, stream>>>(hp_hi, hp_lo, adj_bf, ob);
  ln_gelu_kernel<<<8192, 256, 0, stream>>>(ob, out, gamma, beta);
}

// Round 16
// 187.201 us; speedup vs baseline: 1.2399x; 1.0365x over previous
//
#include <hip/hip_runtime.h>
#include <stdint.h>

// ---------------------------------------------------------------------------
// GraphAttentionLayer fused pipeline, MI355X (gfx950)
// B=64 S=512 C=512 H=4 D=128.  Split-bf16 (hi+lo) 3-term MFMA for GEMM/QK^T.
// Round 16: attn q-tile 128 (4 waves x 32 q via nf=0,1) — K fragments and
// tr_read V fragments are read once per wave and serve 2x the q-work,
// halving the LDS-throughput bound identified as attn's wall.  2 blocks/CU
// (56KB pad) -> 16 (b,h)/XCD = 4.0MB, at the L2 boundary (FETCH = verdict).
// proj (fused cast, r15) and ln (bf16-in) unchanged.
// ---------------------------------------------------------------------------

typedef float  f32x4   __attribute__((ext_vector_type(4)));
typedef short  bf16x8  __attribute__((ext_vector_type(8)));
typedef unsigned short ushort8 __attribute__((ext_vector_type(8)));
typedef unsigned int   uint2v  __attribute__((ext_vector_type(2)));

#define GLD16(src, dst)                                                        \
  __builtin_amdgcn_global_load_lds(                                            \
      (const __attribute__((address_space(1))) void*)(src),                    \
      (__attribute__((address_space(3))) void*)(dst), 16, 0, 0)

__device__ __forceinline__ unsigned short f32_to_bf16(float x) {
  union { float f; unsigned int u; } v; v.f = x;
  unsigned int r = v.u + 0x7FFFu + ((v.u >> 16) & 1u);
  return (unsigned short)(r >> 16);
}
__device__ __forceinline__ float bf16_to_f32(unsigned int h) {
  union { float f; unsigned int u; } v; v.u = h << 16;
  return v.f;
}
__device__ __forceinline__ f32x4 mfma16(bf16x8 a, bf16x8 b, f32x4 c) {
  return __builtin_amdgcn_mfma_f32_16x16x32_bf16(a, b, c, 0, 0, 0);
}
__device__ __forceinline__ float bperm_f(int srcLane, float v) {
  return __int_as_float(__builtin_amdgcn_ds_bpermute(srcLane << 2, __float_as_int(v)));
}
// HW transpose read, canonical per-lane b64 address (base + lane*8B).
__device__ __forceinline__ uint2v tr_read(const unsigned short* p) {
  uint2v r;
  asm volatile("ds_read_b64_tr_b16 %0, %1"
               : "=v"(r)
               : "v"((const __attribute__((address_space(3))) void*)p)
               : "memory");
  return r;
}

// ---------------------------------------------------------------------------
// Kernel 2: W [H,C,D] fp32 -> Wt_hi/lo [H,D,C] bf16 (transposed per head).
// ---------------------------------------------------------------------------
__global__ __launch_bounds__(256) void cast_split_Wt(
    const float* __restrict__ W, unsigned short* __restrict__ whi,
    unsigned short* __restrict__ wlo) {
  int o = blockIdx.x * 256 + threadIdx.x;      // [0, 4*128*512)
  int hd = o >> 16;                             // head
  int rem = o & 65535;
  int d = rem >> 9;                             // [0,128)
  int c = rem & 511;                            // [0,512)
  float v = W[((size_t)(hd * 512 + c)) * 128 + d];
  unsigned short h0 = f32_to_bf16(v);
  whi[o] = h0;
  wlo[o] = f32_to_bf16(v - bf16_to_f32(h0));
}

// ---------------------------------------------------------------------------
// Kernel 2b: adj (fp32) -> bf16 (exact for 0/1 masks).  8 elems/thread.
// ---------------------------------------------------------------------------
__global__ __launch_bounds__(256) void cast_adj(
    const float* __restrict__ src, unsigned short* __restrict__ dst) {
  size_t i = ((size_t)blockIdx.x * 256 + threadIdx.x) * 8;
  f32x4 a = *(const f32x4*)(src + i);
  f32x4 b = *(const f32x4*)(src + i + 4);
  ushort8 o;
#pragma unroll
  for (int e = 0; e < 4; ++e) {
    o[e] = f32_to_bf16(a[e]);
    o[4 + e] = f32_to_bf16(b[e]);
  }
  *(ushort8*)(dst + i) = o;
}

// ---------------------------------------------------------------------------
// Kernel 3: FUSED cast+projection GEMM  hp = split(h) @ Wall + bias
// (r15 version, unchanged).  A reg-staged from f32 h, trunc-split,
// ds_write swizzled; B via GLD16.  128x128 tile, BK=32, 2-barrier K-step.
// ---------------------------------------------------------------------------
__global__ __launch_bounds__(256, 2) void proj_gemm(
    const float* __restrict__ hsrc,
    const unsigned short* __restrict__ whi, const unsigned short* __restrict__ wlo,
    const float* __restrict__ bias, unsigned short* __restrict__ hp_hi,
    unsigned short* __restrict__ hp_lo) {
  int bid = blockIdx.x;
  int swz = (bid & 7) * 128 + (bid >> 3);       // XCD-contiguous work chunks
  int nt = swz & 3, mt = swz >> 2;
  int m0 = mt * 128, n0 = nt * 128;             // n-tile == head nt

  __shared__ alignas(16) unsigned short Ah[4096], Al[4096], Bh[4096], Bl[4096];

  int tid = threadIdx.x, wv = tid >> 6, lane = tid & 63;
  int l15 = lane & 15, l4 = lane >> 4;
  int wr = wv >> 1, wc = wv & 1;
  int arow = tid >> 3;                          // A-stage: 0..31 (+j*32)
  int acol = (tid & 7) * 4;                     // A-stage f32 col

  f32x4 acc[4][4];
#pragma unroll
  for (int a = 0; a < 4; ++a)
#pragma unroll
    for (int b = 0; b < 4; ++b) acc[a][b] = (f32x4){0.f, 0.f, 0.f, 0.f};

  for (int ks = 0; ks < 16; ++ks) {
    int k0 = ks * 32;
    for (int i = wv; i < 16; i += 4) {
      int grp = i >> 3, j = i & 7;
      int row = j * 16 + (lane >> 2);
      int off = (lane & 3) * 16;
      int sw = ((row >> 1) & 3) << 4;
      const unsigned short* sb = grp ? wlo : whi;
      unsigned short* db = grp ? Bl : Bh;
      GLD16((const char*)sb + ((size_t)(nt * 128 + row) * 512 + k0) * 2 + (off ^ sw),
            db + j * 512);
    }
#pragma unroll
    for (int j = 0; j < 4; ++j) {
      int r = j * 32 + arow;
      f32x4 x = *(const f32x4*)(hsrc + (size_t)(m0 + r) * 512 + k0 + acol);
      unsigned ua = __float_as_uint(x[0]), ub = __float_as_uint(x[1]);
      unsigned uc = __float_as_uint(x[2]), ud = __float_as_uint(x[3]);
      uint2 ph, pl;
      ph.x = (ua >> 16) | (ub & 0xFFFF0000u);
      ph.y = (uc >> 16) | (ud & 0xFFFF0000u);
      float ra = x[0] - __uint_as_float(ua & 0xFFFF0000u);
      float rb = x[1] - __uint_as_float(ub & 0xFFFF0000u);
      float rc = x[2] - __uint_as_float(uc & 0xFFFF0000u);
      float rd = x[3] - __uint_as_float(ud & 0xFFFF0000u);
      pl.x = (__float_as_uint(ra) >> 16) | (__float_as_uint(rb) & 0xFFFF0000u);
      pl.y = (__float_as_uint(rc) >> 16) | (__float_as_uint(rd) & 0xFFFF0000u);
      int boff = r * 64 + ((acol * 2) ^ (((r >> 1) & 3) << 4));
      *(uint2*)((char*)Ah + boff) = ph;
      *(uint2*)((char*)Al + boff) = pl;
    }
    __syncthreads();   // drains ds_writes (lgkm) + GLD16s (vm)

    bf16x8 fah[4], fal[4], fbh[4], fbl[4];
#pragma unroll
    for (int f = 0; f < 4; ++f) {
      int mr = wr * 64 + f * 16 + l15;
      int aadr = mr * 64 + ((16 * l4) ^ (((mr >> 1) & 3) << 4));
      fah[f] = *(const bf16x8*)((const char*)Ah + aadr);
      fal[f] = *(const bf16x8*)((const char*)Al + aadr);
      int nr = wc * 64 + f * 16 + l15;
      int badr = nr * 64 + ((16 * l4) ^ (((nr >> 1) & 3) << 4));
      fbh[f] = *(const bf16x8*)((const char*)Bh + badr);
      fbl[f] = *(const bf16x8*)((const char*)Bl + badr);
    }
#pragma unroll
    for (int a = 0; a < 4; ++a)
#pragma unroll
      for (int b = 0; b < 4; ++b) {
        acc[a][b] = mfma16(fah[a], fbh[b], acc[a][b]);
        acc[a][b] = mfma16(fah[a], fbl[b], acc[a][b]);
        acc[a][b] = mfma16(fal[a], fbh[b], acc[a][b]);
      }
    __syncthreads();
  }

  // epilogue: +bias, RNE split, LDS-staged coalesced writes of hp rows.
#pragma unroll
  for (int a = 0; a < 4; ++a) {
    __syncthreads();
#pragma unroll
    for (int b = 0; b < 4; ++b) {
      int cloc = wc * 64 + b * 16 + l15;
      float bv = bias[n0 + cloc];
#pragma unroll
      for (int r = 0; r < 4; ++r) {
        int rloc = wr * 16 + 4 * l4 + r;
        float v = acc[a][b][r] + bv;
        unsigned short hh = f32_to_bf16(v);
        Ah[rloc * 128 + cloc] = hh;
        Al[rloc * 128 + cloc] = f32_to_bf16(v - bf16_to_f32(hh));
      }
    }
    __syncthreads();
    int rr = tid >> 3, c16 = (tid & 7) * 16;
    int mg = m0 + (rr >> 4) * 64 + a * 16 + (rr & 15);
    bf16x8 vh0 = *(const bf16x8*)(Ah + rr * 128 + c16);
    bf16x8 vh1 = *(const bf16x8*)(Ah + rr * 128 + c16 + 8);
    bf16x8 vl0 = *(const bf16x8*)(Al + rr * 128 + c16);
    bf16x8 vl1 = *(const bf16x8*)(Al + rr * 128 + c16 + 8);
    *(bf16x8*)(hp_hi + (size_t)mg * 512 + n0 + c16) = vh0;
    *(bf16x8*)(hp_hi + (size_t)mg * 512 + n0 + c16 + 8) = vh1;
    *(bf16x8*)(hp_lo + (size_t)mg * 512 + n0 + c16) = vl0;
    *(bf16x8*)(hp_lo + (size_t)mg * 512 + n0 + c16 + 8) = vl1;
  }
}

// ---------------------------------------------------------------------------
// Kernel 5: flash attention, q-tile 128.  Block = (b, head, q-tile of 128),
// 4 waves x 32 q (nf=0,1).  K subtiled [8 sd][32 kv][16 d] hi+lo, dbuf.
// K fragments (QK^T) and tr_read V fragments read ONCE per wave, serve both
// nf -> halved LDS traffic per unit work.  PV single-term trunc-bf16(P)@V_hi.
// One barrier/tile + explicit drains (r12-hardened).  56KB pad -> 2 blk/CU.
// bf16 adj in, bf16 out.
// ---------------------------------------------------------------------------
__global__ __launch_bounds__(256, 2) void attn_kernel(
    const unsigned short* __restrict__ hp_hi, const unsigned short* __restrict__ hp_lo,
    const unsigned short* __restrict__ adjb, unsigned short* __restrict__ ob) {
  int bid = blockIdx.x;
  int swz = (bid & 7) * 128 + (bid >> 3);       // 4 q-tiles of one (b,h) per XCD
  int qt = swz & 3;
  int hd = (swz >> 2) & 3;
  int bb = swz >> 4;
  int q0 = qt * 128;

  __shared__ alignas(16) unsigned short SM[28672];     // 56 KB -> 2 blocks/CU
  // buf0: K_hi @0, K_lo @4096 ; buf1: K_hi @8192, K_lo @12288  (u16 offsets)

  int tid = threadIdx.x, w = tid >> 6, lane = tid & 63;
  int l15 = lane & 15, l4 = lane >> 4;
  int qgb = q0 + w * 32 + l15;                  // + nf*16 for the softmax row

  // Q fragments (B-operand: n=q at l&15, k=d contiguous), hi+lo, 2 nf sets
  bf16x8 qh[2][4], ql[2][4];
#pragma unroll
  for (int nf = 0; nf < 2; ++nf) {
    size_t base = ((size_t)bb * 512 + qgb + nf * 16) * 512 + hd * 128 + 8 * l4;
#pragma unroll
    for (int ds = 0; ds < 4; ++ds) {
      qh[nf][ds] = *(const bf16x8*)(hp_hi + base + ds * 32);
      ql[nf][ds] = *(const bf16x8*)(hp_lo + base + ds * 32);
    }
  }

  f32x4 o[2][8];
#pragma unroll
  for (int nf = 0; nf < 2; ++nf)
#pragma unroll
    for (int vf = 0; vf < 8; ++vf) o[nf][vf] = (f32x4){0.f, 0.f, 0.f, 0.f};
  float m_run[2] = {-3.0e38f, -3.0e38f};
  float l_run[2] = {0.f, 0.f};

  // staging roles: w0 K_hi sd0-3, w1 K_hi sd4-7, w2 K_lo sd0-3, w3 K_lo sd4-7
  const unsigned short* ssb = (w & 2) ? hp_lo : hp_hi;
  int sdst = (w & 2) ? 4096 : 0;
  int sdbase = (w & 1) * 4;
  int skv = lane >> 1, sdh = lane & 1;

  // ---- prologue: stage K[0] into buf0 (subtiled)
  {
    size_t rowb = ((size_t)(bb * 512 + skv)) * 1024 + hd * 256 + sdh * 16;
#pragma unroll
    for (int s2 = 0; s2 < 4; ++s2) {
      int sd = sdbase + s2;
      GLD16((const char*)ssb + rowb + sd * 32, SM + sdst + sd * 512);
    }
  }
  asm volatile("s_waitcnt vmcnt(0)" ::: "memory");
  __syncthreads();

  for (int t = 0; t < 16; ++t) {
    int kv0 = t * 32;
    const unsigned short* Kb = SM + ((t & 1) << 13);
    const unsigned short* Khi = Kb;
    const unsigned short* Klo = Kb + 4096;

    // ---- stage K[t+1] into the other buffer
    if (t < 15) {
      unsigned short* Nb = SM + (((t + 1) & 1) << 13) + sdst;
      size_t rowb = ((size_t)(bb * 512 + kv0 + 32 + skv)) * 1024 + hd * 256 + sdh * 16;
#pragma unroll
      for (int s2 = 0; s2 < 4; ++s2) {
        int sd = sdbase + s2;
        GLD16((const char*)ssb + rowb + sd * 32, Nb + sd * 512);
      }
    }
    // adj loads early (bf16, 2 nf rows)
    uint2 ua[2][2];
#pragma unroll
    for (int nf = 0; nf < 2; ++nf) {
      const unsigned short* ab = adjb + (size_t)(qgb + nf * 16) * 512 + kv0;
      ua[nf][0] = *(const uint2*)(ab + 4 * l4);
      ua[nf][1] = *(const uint2*)(ab + 16 + 4 * l4);
    }

    // ---- QK^T (swapped): K fragments read once, used by both nf
    f32x4 sc[2][2];
#pragma unroll
    for (int nf = 0; nf < 2; ++nf)
#pragma unroll
      for (int mf = 0; mf < 2; ++mf) sc[nf][mf] = (f32x4){0.f, 0.f, 0.f, 0.f};
#pragma unroll
    for (int ds = 0; ds < 4; ++ds) {
      int boff = (2 * ds + (l4 >> 1)) * 1024 + 16 * (l4 & 1);
      int a0 = boff + l15 * 32;
      int a1 = boff + (16 + l15) * 32;
      bf16x8 kh0 = *(const bf16x8*)((const char*)Khi + a0);
      bf16x8 kl0 = *(const bf16x8*)((const char*)Klo + a0);
      bf16x8 kh1 = *(const bf16x8*)((const char*)Khi + a1);
      bf16x8 kl1 = *(const bf16x8*)((const char*)Klo + a1);
#pragma unroll
      for (int nf = 0; nf < 2; ++nf) {
        sc[nf][0] = mfma16(kh0, qh[nf][ds], sc[nf][0]);
        sc[nf][1] = mfma16(kh1, qh[nf][ds], sc[nf][1]);
        sc[nf][0] = mfma16(kh0, ql[nf][ds], sc[nf][0]);
        sc[nf][1] = mfma16(kh1, ql[nf][ds], sc[nf][1]);
        sc[nf][0] = mfma16(kl0, qh[nf][ds], sc[nf][0]);
        sc[nf][1] = mfma16(kl1, qh[nf][ds], sc[nf][1]);
      }
    }

    // ---- adj multiply + online softmax + pack, per nf (independent chains)
    union PU { bf16x8 v; unsigned u[4]; } pah[2];
#pragma unroll
    for (int nf = 0; nf < 2; ++nf) {
      f32x4 av0, av1;
      av0[0] = bf16_to_f32(ua[nf][0].x & 0xFFFFu);
      av0[1] = bf16_to_f32(ua[nf][0].x >> 16);
      av0[2] = bf16_to_f32(ua[nf][0].y & 0xFFFFu);
      av0[3] = bf16_to_f32(ua[nf][0].y >> 16);
      av1[0] = bf16_to_f32(ua[nf][1].x & 0xFFFFu);
      av1[1] = bf16_to_f32(ua[nf][1].x >> 16);
      av1[2] = bf16_to_f32(ua[nf][1].y & 0xFFFFu);
      av1[3] = bf16_to_f32(ua[nf][1].y >> 16);
      float p0[4], p1[4];
      float tm = -3.0e38f;
#pragma unroll
      for (int r = 0; r < 4; ++r) {
        p0[r] = sc[nf][0][r] * av0[r];
        p1[r] = sc[nf][1][r] * av1[r];
        tm = fmaxf(tm, fmaxf(p0[r], p1[r]));
      }
      tm = fmaxf(tm, __shfl_xor(tm, 16));
      tm = fmaxf(tm, __shfl_xor(tm, 32));
      if (__any(tm > m_run[nf] + 8.0f)) {       // T13 defer-rescale
        float mn = fmaxf(m_run[nf], tm);
        float scl = __expf(m_run[nf] - mn);
        m_run[nf] = mn;
        l_run[nf] *= scl;
        f32x4 s4;
#pragma unroll
        for (int r = 0; r < 4; ++r) s4[r] = bperm_f(4 * l4 + r, scl);
#pragma unroll
        for (int vf = 0; vf < 8; ++vf)
#pragma unroll
          for (int r = 0; r < 4; ++r) o[nf][vf][r] *= s4[r];
      }
      float ps = 0.f;
#pragma unroll
      for (int r = 0; r < 4; ++r) {
        p0[r] = __expf(p0[r] - m_run[nf]); ps += p0[r];
        p1[r] = __expf(p1[r] - m_run[nf]); ps += p1[r];
      }
      ps += __shfl_xor(ps, 16);
      ps += __shfl_xor(ps, 32);
      l_run[nf] += ps;
#pragma unroll
      for (int i = 0; i < 4; ++i) {
        float fa = (i < 2) ? p0[2 * i] : p1[2 * (i - 2)];
        float fb = (i < 2) ? p0[2 * i + 1] : p1[2 * (i - 2) + 1];
        pah[nf].u[i] = (__float_as_uint(fa) >> 16) |
                       (__float_as_uint(fb) & 0xFFFF0000u);
      }
    }

    // ---- O += P @ V_hi: V fragments via tr_read, read once, serve both nf
    const unsigned short* trb = Khi + lane * 4;
    union VU { bf16x8 v; uint2v u2[2]; } vh[8];
#pragma unroll
    for (int vf = 0; vf < 8; ++vf) {
      vh[vf].u2[0] = tr_read(trb + vf * 512);
      vh[vf].u2[1] = tr_read(trb + vf * 512 + 256);
    }
    asm volatile("s_waitcnt lgkmcnt(0)" ::: "memory");
    __builtin_amdgcn_sched_barrier(0);
#pragma unroll
    for (int vf = 0; vf < 8; ++vf) {
      o[0][vf] = mfma16(pah[0].v, vh[vf].v, o[0][vf]);
      o[1][vf] = mfma16(pah[1].v, vh[vf].v, o[1][vf]);
    }
    asm volatile("s_waitcnt vmcnt(0) lgkmcnt(0)" ::: "memory");
    __syncthreads();   // K[t+1] visible; WAR turnover on buf[t&1]
  }

  // ---- epilogue: 2 passes (nf), wave-private LDS chunk, coalesced bf16 out
#pragma unroll
  for (int nf = 0; nf < 2; ++nf) {
    float rinv = 1.0f / l_run[nf];
    f32x4 r4;
#pragma unroll
    for (int r = 0; r < 4; ++r) r4[r] = bperm_f(4 * l4 + r, rinv);
    float* wbase = (float*)SM + w * 2048;       // [16][128] f32 per wave
#pragma unroll
    for (int vf = 0; vf < 8; ++vf)
#pragma unroll
      for (int r = 0; r < 4; ++r)
        wbase[(4 * l4 + r) * 128 + vf * 16 + l15] = o[nf][vf][r] * r4[r];
    __syncthreads();
#pragma unroll
    for (int p = 0; p < 4; ++p) {
      int row = p * 4 + l4;
      f32x4 v0 = *(const f32x4*)(wbase + row * 128 + l15 * 8);
      f32x4 v1 = *(const f32x4*)(wbase + row * 128 + l15 * 8 + 4);
      ushort8 o8;
#pragma unroll
      for (int e = 0; e < 4; ++e) {
        o8[e] = f32_to_bf16(v0[e]);
        o8[4 + e] = f32_to_bf16(v1[e]);
      }
      size_t mg = (size_t)bb * 512 + q0 + w * 32 + nf * 16 + row;
      *(ushort8*)(ob + mg * 512 + hd * 128 + l15 * 8) = o8;
    }
    __syncthreads();
  }
}

// ---------------------------------------------------------------------------
// Kernel 6: LayerNorm (over C=512) + exact-erf GELU.  bf16 in, fp32 out.
// ---------------------------------------------------------------------------
__global__ __launch_bounds__(256) void ln_gelu_kernel(
    const unsigned short* __restrict__ in, float* __restrict__ outp,
    const float* __restrict__ gamma, const float* __restrict__ beta) {
  int w = threadIdx.x >> 6, lane = threadIdx.x & 63;
  size_t row = (size_t)blockIdx.x * 4 + w;
  ushort8 v = *(const ushort8*)(in + row * 512 + lane * 8);
  float x[8];
#pragma unroll
  for (int e = 0; e < 8; ++e) x[e] = bf16_to_f32((unsigned int)(unsigned short)v[e]);
  float s = 0.f;
#pragma unroll
  for (int e = 0; e < 8; ++e) s += x[e];
#pragma unroll
  for (int off = 32; off >= 1; off >>= 1) s += __shfl_xor(s, off);
  float mu = s * (1.0f / 512.0f);
  float vs = 0.f;
#pragma unroll
  for (int e = 0; e < 8; ++e) {
    float d = x[e] - mu; vs += d * d;
  }
#pragma unroll
  for (int off = 32; off >= 1; off >>= 1) vs += __shfl_xor(vs, off);
  float rs = rsqrtf(vs * (1.0f / 512.0f) + 1e-5f);
  f32x4 g0 = *(const f32x4*)(gamma + lane * 8);
  f32x4 g1 = *(const f32x4*)(gamma + lane * 8 + 4);
  f32x4 b0 = *(const f32x4*)(beta + lane * 8);
  f32x4 b1 = *(const f32x4*)(beta + lane * 8 + 4);
  f32x4 y0, y1;
#pragma unroll
  for (int e = 0; e < 4; ++e) {
    float y = (x[e] - mu) * rs * g0[e] + b0[e];
    y0[e] = 0.5f * y * (1.0f + erff(y * 0.70710678118654752f));
    float z = (x[4 + e] - mu) * rs * g1[e] + b1[e];
    y1[e] = 0.5f * z * (1.0f + erff(z * 0.70710678118654752f));
  }
  float* p = outp + row * 512 + lane * 8;
  *(f32x4*)p = y0;
  *(f32x4*)(p + 4) = y1;
}

// ---------------------------------------------------------------------------
// Host launcher.  Inputs: [0]=t [1]=h [2]=W [3]=b [4]=adj [5]=gamma [6]=beta
// Workspace (~129 MB):
//   adj_bf = ws + 0          (262144 u16)
//   ob     = ws + 16777216   (16.7M u16, bf16 attn out)
//   hp_hi  = ws + 33554432
//   hp_lo  = ws + 50331648
//   Wt_hi  = ws + 67108864   (262144 u16)
//   Wt_lo  = ws + 67371008
// ---------------------------------------------------------------------------
extern "C" void kernel_launch(void* const* d_in, const int* in_sizes, int n_in,
                              void* d_out, int out_size, void* d_ws, size_t ws_size,
                              hipStream_t stream) {
  const float* h     = (const float*)d_in[1];
  const float* W     = (const float*)d_in[2];
  const float* bias  = (const float*)d_in[3];
  const float* adj   = (const float*)d_in[4];
  const float* gamma = (const float*)d_in[5];
  const float* beta  = (const float*)d_in[6];
  float* out = (float*)d_out;

  unsigned short* ws = (unsigned short*)d_ws;
  unsigned short* adj_bf = ws;
  unsigned short* ob     = ws + 16777216;
  unsigned short* hp_hi  = ws + 33554432;
  unsigned short* hp_lo  = ws + 50331648;
  unsigned short* Wt_hi  = ws + 67108864;
  unsigned short* Wt_lo  = ws + 67371008;

  cast_split_Wt<<<1024, 256, 0, stream>>>(W, Wt_hi, Wt_lo);
  cast_adj<<<128, 256, 0, stream>>>(adj, adj_bf);
  proj_gemm<<<1024, 256, 0, stream>>>(h, Wt_hi, Wt_lo, bias, hp_hi, hp_lo);
  attn_kernel<<<1024, 256, 0, stream>>>(hp_hi, hp_lo, adj_bf, ob);
  ln_gelu_kernel<<<8192, 256, 0, stream>>>(ob, out, gamma, beta);
}

// Round 17
// 186.046 us; speedup vs baseline: 1.2476x; 1.0062x over previous
//
#include <hip/hip_runtime.h>
#include <stdint.h>

// ---------------------------------------------------------------------------
// GraphAttentionLayer fused pipeline, MI355X (gfx950)
// B=64 S=512 C=512 H=4 D=128.  Split-bf16 (hi+lo) 3-term MFMA for GEMM/QK^T.
// Round 17: proj K-loop rebuilt with counted-vmcnt pipeline (T4/T14): B GLD16
// issued first, A[ks+1] f32 prefetch into regs, s_waitcnt vmcnt(4) + RAW
// s_barrier (never drains the prefetch mid-loop); barrier-2 lgkm-only.
// attn (q-tile 128, r16) / ln / casts unchanged.
// ---------------------------------------------------------------------------

typedef float  f32x4   __attribute__((ext_vector_type(4)));
typedef short  bf16x8  __attribute__((ext_vector_type(8)));
typedef unsigned short ushort8 __attribute__((ext_vector_type(8)));
typedef unsigned int   uint2v  __attribute__((ext_vector_type(2)));

#define GLD16(src, dst)                                                        \
  __builtin_amdgcn_global_load_lds(                                            \
      (const __attribute__((address_space(1))) void*)(src),                    \
      (__attribute__((address_space(3))) void*)(dst), 16, 0, 0)

__device__ __forceinline__ unsigned short f32_to_bf16(float x) {
  union { float f; unsigned int u; } v; v.f = x;
  unsigned int r = v.u + 0x7FFFu + ((v.u >> 16) & 1u);
  return (unsigned short)(r >> 16);
}
__device__ __forceinline__ float bf16_to_f32(unsigned int h) {
  union { float f; unsigned int u; } v; v.u = h << 16;
  return v.f;
}
__device__ __forceinline__ f32x4 mfma16(bf16x8 a, bf16x8 b, f32x4 c) {
  return __builtin_amdgcn_mfma_f32_16x16x32_bf16(a, b, c, 0, 0, 0);
}
__device__ __forceinline__ float bperm_f(int srcLane, float v) {
  return __int_as_float(__builtin_amdgcn_ds_bpermute(srcLane << 2, __float_as_int(v)));
}
// HW transpose read, canonical per-lane b64 address (base + lane*8B).
__device__ __forceinline__ uint2v tr_read(const unsigned short* p) {
  uint2v r;
  asm volatile("ds_read_b64_tr_b16 %0, %1"
               : "=v"(r)
               : "v"((const __attribute__((address_space(3))) void*)p)
               : "memory");
  return r;
}

// ---------------------------------------------------------------------------
// Kernel 2: W [H,C,D] fp32 -> Wt_hi/lo [H,D,C] bf16 (transposed per head).
// ---------------------------------------------------------------------------
__global__ __launch_bounds__(256) void cast_split_Wt(
    const float* __restrict__ W, unsigned short* __restrict__ whi,
    unsigned short* __restrict__ wlo) {
  int o = blockIdx.x * 256 + threadIdx.x;      // [0, 4*128*512)
  int hd = o >> 16;                             // head
  int rem = o & 65535;
  int d = rem >> 9;                             // [0,128)
  int c = rem & 511;                            // [0,512)
  float v = W[((size_t)(hd * 512 + c)) * 128 + d];
  unsigned short h0 = f32_to_bf16(v);
  whi[o] = h0;
  wlo[o] = f32_to_bf16(v - bf16_to_f32(h0));
}

// ---------------------------------------------------------------------------
// Kernel 2b: adj (fp32) -> bf16 (exact for 0/1 masks).  8 elems/thread.
// ---------------------------------------------------------------------------
__global__ __launch_bounds__(256) void cast_adj(
    const float* __restrict__ src, unsigned short* __restrict__ dst) {
  size_t i = ((size_t)blockIdx.x * 256 + threadIdx.x) * 8;
  f32x4 a = *(const f32x4*)(src + i);
  f32x4 b = *(const f32x4*)(src + i + 4);
  ushort8 o;
#pragma unroll
  for (int e = 0; e < 4; ++e) {
    o[e] = f32_to_bf16(a[e]);
    o[4 + e] = f32_to_bf16(b[e]);
  }
  *(ushort8*)(dst + i) = o;
}

// ---------------------------------------------------------------------------
// Kernel 3: FUSED cast+projection GEMM  hp = split(h) @ Wall + bias.
// Counted-vmcnt pipeline: per K-step  {issue B GLD16 (oldest) -> ds_write
// A[ks] from regs -> issue A[ks+1] f32 loads -> vmcnt(4)+lgkm(0) + raw
// s_barrier -> frag reads + MFMA -> lgkm(0) + raw s_barrier}.  The A
// prefetch is never drained mid-loop (T4).  128x128 tile, BK=32, 4 waves.
// ---------------------------------------------------------------------------
__global__ __launch_bounds__(256, 2) void proj_gemm(
    const float* __restrict__ hsrc,
    const unsigned short* __restrict__ whi, const unsigned short* __restrict__ wlo,
    const float* __restrict__ bias, unsigned short* __restrict__ hp_hi,
    unsigned short* __restrict__ hp_lo) {
  int bid = blockIdx.x;
  int swz = (bid & 7) * 128 + (bid >> 3);       // XCD-contiguous work chunks
  int nt = swz & 3, mt = swz >> 2;
  int m0 = mt * 128, n0 = nt * 128;             // n-tile == head nt

  __shared__ alignas(16) unsigned short Ah[4096], Al[4096], Bh[4096], Bl[4096];

  int tid = threadIdx.x, wv = tid >> 6, lane = tid & 63;
  int l15 = lane & 15, l4 = lane >> 4;
  int wr = wv >> 1, wc = wv & 1;
  int arow = tid >> 3;                          // A-stage: 0..31 (+j*32)
  int acol = (tid & 7) * 4;                     // A-stage f32 col

  f32x4 acc[4][4];
#pragma unroll
  for (int a = 0; a < 4; ++a)
#pragma unroll
    for (int b = 0; b < 4; ++b) acc[a][b] = (f32x4){0.f, 0.f, 0.f, 0.f};

  // ---- prologue: A[0] into regs
  f32x4 areg[4];
#pragma unroll
  for (int j = 0; j < 4; ++j)
    areg[j] = *(const f32x4*)(hsrc + (size_t)(m0 + j * 32 + arow) * 512 + acol);

  for (int ks = 0; ks < 16; ++ks) {
    int k0 = ks * 32;
    // 1) B staging via GLD16 (issued first = oldest vm ops)
    for (int i = wv; i < 16; i += 4) {
      int grp = i >> 3, j = i & 7;
      int row = j * 16 + (lane >> 2);
      int off = (lane & 3) * 16;
      int sw = ((row >> 1) & 3) << 4;
      const unsigned short* sb = grp ? wlo : whi;
      unsigned short* db = grp ? Bl : Bh;
      GLD16((const char*)sb + ((size_t)(nt * 128 + row) * 512 + k0) * 2 + (off ^ sw),
            db + j * 512);
    }
    // 2) split A[ks] regs -> swizzled ds_write
#pragma unroll
    for (int j = 0; j < 4; ++j) {
      int r = j * 32 + arow;
      f32x4 x = areg[j];
      unsigned ua = __float_as_uint(x[0]), ub = __float_as_uint(x[1]);
      unsigned uc = __float_as_uint(x[2]), ud = __float_as_uint(x[3]);
      uint2 ph, pl;
      ph.x = (ua >> 16) | (ub & 0xFFFF0000u);
      ph.y = (uc >> 16) | (ud & 0xFFFF0000u);
      float ra = x[0] - __uint_as_float(ua & 0xFFFF0000u);
      float rb = x[1] - __uint_as_float(ub & 0xFFFF0000u);
      float rc = x[2] - __uint_as_float(uc & 0xFFFF0000u);
      float rd = x[3] - __uint_as_float(ud & 0xFFFF0000u);
      pl.x = (__float_as_uint(ra) >> 16) | (__float_as_uint(rb) & 0xFFFF0000u);
      pl.y = (__float_as_uint(rc) >> 16) | (__float_as_uint(rd) & 0xFFFF0000u);
      int boff = r * 64 + ((acol * 2) ^ (((r >> 1) & 3) << 4));
      *(uint2*)((char*)Ah + boff) = ph;
      *(uint2*)((char*)Al + boff) = pl;
    }
    // 3) issue A[ks+1] prefetch (4 global loads, youngest vm ops)
    if (ks < 15) {
#pragma unroll
      for (int j = 0; j < 4; ++j)
        areg[j] = *(const f32x4*)(hsrc + (size_t)(m0 + j * 32 + arow) * 512 +
                                  k0 + 32 + acol);
    }
    // 4) counted drain: B done + ds_writes visible; A-prefetch stays in flight
    if (ks < 15) {
      asm volatile("s_waitcnt vmcnt(4) lgkmcnt(0)" ::: "memory");
    } else {
      asm volatile("s_waitcnt vmcnt(0) lgkmcnt(0)" ::: "memory");
    }
    __builtin_amdgcn_s_barrier();
    __builtin_amdgcn_sched_barrier(0);

    // 5) fragment reads + MFMA
    bf16x8 fah[4], fal[4], fbh[4], fbl[4];
#pragma unroll
    for (int f = 0; f < 4; ++f) {
      int mr = wr * 64 + f * 16 + l15;
      int aadr = mr * 64 + ((16 * l4) ^ (((mr >> 1) & 3) << 4));
      fah[f] = *(const bf16x8*)((const char*)Ah + aadr);
      fal[f] = *(const bf16x8*)((const char*)Al + aadr);
      int nr = wc * 64 + f * 16 + l15;
      int badr = nr * 64 + ((16 * l4) ^ (((nr >> 1) & 3) << 4));
      fbh[f] = *(const bf16x8*)((const char*)Bh + badr);
      fbl[f] = *(const bf16x8*)((const char*)Bl + badr);
    }
#pragma unroll
    for (int a = 0; a < 4; ++a)
#pragma unroll
      for (int b = 0; b < 4; ++b) {
        acc[a][b] = mfma16(fah[a], fbh[b], acc[a][b]);
        acc[a][b] = mfma16(fah[a], fbl[b], acc[a][b]);
        acc[a][b] = mfma16(fal[a], fbh[b], acc[a][b]);
      }
    // 6) WAR fence: own LDS reads done; do NOT drain vmcnt (prefetch flying)
    asm volatile("s_waitcnt lgkmcnt(0)" ::: "memory");
    __builtin_amdgcn_s_barrier();
    __builtin_amdgcn_sched_barrier(0);
  }

  __syncthreads();   // full drain before epilogue reuses Ah/Al

  // epilogue: +bias, RNE split, LDS-staged coalesced writes of hp rows.
#pragma unroll
  for (int a = 0; a < 4; ++a) {
    __syncthreads();
#pragma unroll
    for (int b = 0; b < 4; ++b) {
      int cloc = wc * 64 + b * 16 + l15;
      float bv = bias[n0 + cloc];
#pragma unroll
      for (int r = 0; r < 4; ++r) {
        int rloc = wr * 16 + 4 * l4 + r;
        float v = acc[a][b][r] + bv;
        unsigned short hh = f32_to_bf16(v);
        Ah[rloc * 128 + cloc] = hh;
        Al[rloc * 128 + cloc] = f32_to_bf16(v - bf16_to_f32(hh));
      }
    }
    __syncthreads();
    int rr = tid >> 3, c16 = (tid & 7) * 16;
    int mg = m0 + (rr >> 4) * 64 + a * 16 + (rr & 15);
    bf16x8 vh0 = *(const bf16x8*)(Ah + rr * 128 + c16);
    bf16x8 vh1 = *(const bf16x8*)(Ah + rr * 128 + c16 + 8);
    bf16x8 vl0 = *(const bf16x8*)(Al + rr * 128 + c16);
    bf16x8 vl1 = *(const bf16x8*)(Al + rr * 128 + c16 + 8);
    *(bf16x8*)(hp_hi + (size_t)mg * 512 + n0 + c16) = vh0;
    *(bf16x8*)(hp_hi + (size_t)mg * 512 + n0 + c16 + 8) = vh1;
    *(bf16x8*)(hp_lo + (size_t)mg * 512 + n0 + c16) = vl0;
    *(bf16x8*)(hp_lo + (size_t)mg * 512 + n0 + c16 + 8) = vl1;
  }
}

// ---------------------------------------------------------------------------
// Kernel 5: flash attention, q-tile 128 (r16, unchanged).  4 waves x 32 q
// (nf=0,1).  K subtiled [8 sd][32 kv][16 d] hi+lo, dbuf.  K/V fragments read
// once per wave, serve both nf.  PV single-term trunc-bf16(P)@V_hi.  One
// barrier/tile + explicit drains.  56KB pad -> 2 blk/CU.  bf16 adj/out.
// ---------------------------------------------------------------------------
__global__ __launch_bounds__(256, 2) void attn_kernel(
    const unsigned short* __restrict__ hp_hi, const unsigned short* __restrict__ hp_lo,
    const unsigned short* __restrict__ adjb, unsigned short* __restrict__ ob) {
  int bid = blockIdx.x;
  int swz = (bid & 7) * 128 + (bid >> 3);       // 4 q-tiles of one (b,h) per XCD
  int qt = swz & 3;
  int hd = (swz >> 2) & 3;
  int bb = swz >> 4;
  int q0 = qt * 128;

  __shared__ alignas(16) unsigned short SM[28672];     // 56 KB -> 2 blocks/CU

  int tid = threadIdx.x, w = tid >> 6, lane = tid & 63;
  int l15 = lane & 15, l4 = lane >> 4;
  int qgb = q0 + w * 32 + l15;                  // + nf*16 for the softmax row

  bf16x8 qh[2][4], ql[2][4];
#pragma unroll
  for (int nf = 0; nf < 2; ++nf) {
    size_t base = ((size_t)bb * 512 + qgb + nf * 16) * 512 + hd * 128 + 8 * l4;
#pragma unroll
    for (int ds = 0; ds < 4; ++ds) {
      qh[nf][ds] = *(const bf16x8*)(hp_hi + base + ds * 32);
      ql[nf][ds] = *(const bf16x8*)(hp_lo + base + ds * 32);
    }
  }

  f32x4 o[2][8];
#pragma unroll
  for (int nf = 0; nf < 2; ++nf)
#pragma unroll
    for (int vf = 0; vf < 8; ++vf) o[nf][vf] = (f32x4){0.f, 0.f, 0.f, 0.f};
  float m_run[2] = {-3.0e38f, -3.0e38f};
  float l_run[2] = {0.f, 0.f};

  const unsigned short* ssb = (w & 2) ? hp_lo : hp_hi;
  int sdst = (w & 2) ? 4096 : 0;
  int sdbase = (w & 1) * 4;
  int skv = lane >> 1, sdh = lane & 1;

  {
    size_t rowb = ((size_t)(bb * 512 + skv)) * 1024 + hd * 256 + sdh * 16;
#pragma unroll
    for (int s2 = 0; s2 < 4; ++s2) {
      int sd = sdbase + s2;
      GLD16((const char*)ssb + rowb + sd * 32, SM + sdst + sd * 512);
    }
  }
  asm volatile("s_waitcnt vmcnt(0)" ::: "memory");
  __syncthreads();

  for (int t = 0; t < 16; ++t) {
    int kv0 = t * 32;
    const unsigned short* Kb = SM + ((t & 1) << 13);
    const unsigned short* Khi = Kb;
    const unsigned short* Klo = Kb + 4096;

    if (t < 15) {
      unsigned short* Nb = SM + (((t + 1) & 1) << 13) + sdst;
      size_t rowb = ((size_t)(bb * 512 + kv0 + 32 + skv)) * 1024 + hd * 256 + sdh * 16;
#pragma unroll
      for (int s2 = 0; s2 < 4; ++s2) {
        int sd = sdbase + s2;
        GLD16((const char*)ssb + rowb + sd * 32, Nb + sd * 512);
      }
    }
    uint2 ua[2][2];
#pragma unroll
    for (int nf = 0; nf < 2; ++nf) {
      const unsigned short* ab = adjb + (size_t)(qgb + nf * 16) * 512 + kv0;
      ua[nf][0] = *(const uint2*)(ab + 4 * l4);
      ua[nf][1] = *(const uint2*)(ab + 16 + 4 * l4);
    }

    f32x4 sc[2][2];
#pragma unroll
    for (int nf = 0; nf < 2; ++nf)
#pragma unroll
      for (int mf = 0; mf < 2; ++mf) sc[nf][mf] = (f32x4){0.f, 0.f, 0.f, 0.f};
#pragma unroll
    for (int ds = 0; ds < 4; ++ds) {
      int boff = (2 * ds + (l4 >> 1)) * 1024 + 16 * (l4 & 1);
      int a0 = boff + l15 * 32;
      int a1 = boff + (16 + l15) * 32;
      bf16x8 kh0 = *(const bf16x8*)((const char*)Khi + a0);
      bf16x8 kl0 = *(const bf16x8*)((const char*)Klo + a0);
      bf16x8 kh1 = *(const bf16x8*)((const char*)Khi + a1);
      bf16x8 kl1 = *(const bf16x8*)((const char*)Klo + a1);
#pragma unroll
      for (int nf = 0; nf < 2; ++nf) {
        sc[nf][0] = mfma16(kh0, qh[nf][ds], sc[nf][0]);
        sc[nf][1] = mfma16(kh1, qh[nf][ds], sc[nf][1]);
        sc[nf][0] = mfma16(kh0, ql[nf][ds], sc[nf][0]);
        sc[nf][1] = mfma16(kh1, ql[nf][ds], sc[nf][1]);
        sc[nf][0] = mfma16(kl0, qh[nf][ds], sc[nf][0]);
        sc[nf][1] = mfma16(kl1, qh[nf][ds], sc[nf][1]);
      }
    }

    union PU { bf16x8 v; unsigned u[4]; } pah[2];
#pragma unroll
    for (int nf = 0; nf < 2; ++nf) {
      f32x4 av0, av1;
      av0[0] = bf16_to_f32(ua[nf][0].x & 0xFFFFu);
      av0[1] = bf16_to_f32(ua[nf][0].x >> 16);
      av0[2] = bf16_to_f32(ua[nf][0].y & 0xFFFFu);
      av0[3] = bf16_to_f32(ua[nf][0].y >> 16);
      av1[0] = bf16_to_f32(ua[nf][1].x & 0xFFFFu);
      av1[1] = bf16_to_f32(ua[nf][1].x >> 16);
      av1[2] = bf16_to_f32(ua[nf][1].y & 0xFFFFu);
      av1[3] = bf16_to_f32(ua[nf][1].y >> 16);
      float p0[4], p1[4];
      float tm = -3.0e38f;
#pragma unroll
      for (int r = 0; r < 4; ++r) {
        p0[r] = sc[nf][0][r] * av0[r];
        p1[r] = sc[nf][1][r] * av1[r];
        tm = fmaxf(tm, fmaxf(p0[r], p1[r]));
      }
      tm = fmaxf(tm, __shfl_xor(tm, 16));
      tm = fmaxf(tm, __shfl_xor(tm, 32));
      if (__any(tm > m_run[nf] + 8.0f)) {       // T13 defer-rescale
        float mn = fmaxf(m_run[nf], tm);
        float scl = __expf(m_run[nf] - mn);
        m_run[nf] = mn;
        l_run[nf] *= scl;
        f32x4 s4;
#pragma unroll
        for (int r = 0; r < 4; ++r) s4[r] = bperm_f(4 * l4 + r, scl);
#pragma unroll
        for (int vf = 0; vf < 8; ++vf)
#pragma unroll
          for (int r = 0; r < 4; ++r) o[nf][vf][r] *= s4[r];
      }
      float ps = 0.f;
#pragma unroll
      for (int r = 0; r < 4; ++r) {
        p0[r] = __expf(p0[r] - m_run[nf]); ps += p0[r];
        p1[r] = __expf(p1[r] - m_run[nf]); ps += p1[r];
      }
      ps += __shfl_xor(ps, 16);
      ps += __shfl_xor(ps, 32);
      l_run[nf] += ps;
#pragma unroll
      for (int i = 0; i < 4; ++i) {
        float fa = (i < 2) ? p0[2 * i] : p1[2 * (i - 2)];
        float fb = (i < 2) ? p0[2 * i + 1] : p1[2 * (i - 2) + 1];
        pah[nf].u[i] = (__float_as_uint(fa) >> 16) |
                       (__float_as_uint(fb) & 0xFFFF0000u);
      }
    }

    const unsigned short* trb = Khi + lane * 4;
    union VU { bf16x8 v; uint2v u2[2]; } vh[8];
#pragma unroll
    for (int vf = 0; vf < 8; ++vf) {
      vh[vf].u2[0] = tr_read(trb + vf * 512);
      vh[vf].u2[1] = tr_read(trb + vf * 512 + 256);
    }
    asm volatile("s_waitcnt lgkmcnt(0)" ::: "memory");
    __builtin_amdgcn_sched_barrier(0);
#pragma unroll
    for (int vf = 0; vf < 8; ++vf) {
      o[0][vf] = mfma16(pah[0].v, vh[vf].v, o[0][vf]);
      o[1][vf] = mfma16(pah[1].v, vh[vf].v, o[1][vf]);
    }
    asm volatile("s_waitcnt vmcnt(0) lgkmcnt(0)" ::: "memory");
    __syncthreads();
  }

  // ---- epilogue: 2 passes (nf), wave-private LDS chunk, coalesced bf16 out
#pragma unroll
  for (int nf = 0; nf < 2; ++nf) {
    float rinv = 1.0f / l_run[nf];
    f32x4 r4;
#pragma unroll
    for (int r = 0; r < 4; ++r) r4[r] = bperm_f(4 * l4 + r, rinv);
    float* wbase = (float*)SM + w * 2048;       // [16][128] f32 per wave
#pragma unroll
    for (int vf = 0; vf < 8; ++vf)
#pragma unroll
      for (int r = 0; r < 4; ++r)
        wbase[(4 * l4 + r) * 128 + vf * 16 + l15] = o[nf][vf][r] * r4[r];
    __syncthreads();
#pragma unroll
    for (int p = 0; p < 4; ++p) {
      int row = p * 4 + l4;
      f32x4 v0 = *(const f32x4*)(wbase + row * 128 + l15 * 8);
      f32x4 v1 = *(const f32x4*)(wbase + row * 128 + l15 * 8 + 4);
      ushort8 o8;
#pragma unroll
      for (int e = 0; e < 4; ++e) {
        o8[e] = f32_to_bf16(v0[e]);
        o8[4 + e] = f32_to_bf16(v1[e]);
      }
      size_t mg = (size_t)bb * 512 + q0 + w * 32 + nf * 16 + row;
      *(ushort8*)(ob + mg * 512 + hd * 128 + l15 * 8) = o8;
    }
    __syncthreads();
  }
}

// ---------------------------------------------------------------------------
// Kernel 6: LayerNorm (over C=512) + exact-erf GELU.  bf16 in, fp32 out.
// ---------------------------------------------------------------------------
__global__ __launch_bounds__(256) void ln_gelu_kernel(
    const unsigned short* __restrict__ in, float* __restrict__ outp,
    const float* __restrict__ gamma, const float* __restrict__ beta) {
  int w = threadIdx.x >> 6, lane = threadIdx.x & 63;
  size_t row = (size_t)blockIdx.x * 4 + w;
  ushort8 v = *(const ushort8*)(in + row * 512 + lane * 8);
  float x[8];
#pragma unroll
  for (int e = 0; e < 8; ++e) x[e] = bf16_to_f32((unsigned int)(unsigned short)v[e]);
  float s = 0.f;
#pragma unroll
  for (int e = 0; e < 8; ++e) s += x[e];
#pragma unroll
  for (int off = 32; off >= 1; off >>= 1) s += __shfl_xor(s, off);
  float mu = s * (1.0f / 512.0f);
  float vs = 0.f;
#pragma unroll
  for (int e = 0; e < 8; ++e) {
    float d = x[e] - mu; vs += d * d;
  }
#pragma unroll
  for (int off = 32; off >= 1; off >>= 1) vs += __shfl_xor(vs, off);
  float rs = rsqrtf(vs * (1.0f / 512.0f) + 1e-5f);
  f32x4 g0 = *(const f32x4*)(gamma + lane * 8);
  f32x4 g1 = *(const f32x4*)(gamma + lane * 8 + 4);
  f32x4 b0 = *(const f32x4*)(beta + lane * 8);
  f32x4 b1 = *(const f32x4*)(beta + lane * 8 + 4);
  f32x4 y0, y1;
#pragma unroll
  for (int e = 0; e < 4; ++e) {
    float y = (x[e] - mu) * rs * g0[e] + b0[e];
    y0[e] = 0.5f * y * (1.0f + erff(y * 0.70710678118654752f));
    float z = (x[4 + e] - mu) * rs * g1[e] + b1[e];
    y1[e] = 0.5f * z * (1.0f + erff(z * 0.70710678118654752f));
  }
  float* p = outp + row * 512 + lane * 8;
  *(f32x4*)p = y0;
  *(f32x4*)(p + 4) = y1;
}

// ---------------------------------------------------------------------------
// Host launcher.  Inputs: [0]=t [1]=h [2]=W [3]=b [4]=adj [5]=gamma [6]=beta
// Workspace (~129 MB):
//   adj_bf = ws + 0          (262144 u16)
//   ob     = ws + 16777216   (16.7M u16, bf16 attn out)
//   hp_hi  = ws + 33554432
//   hp_lo  = ws + 50331648
//   Wt_hi  = ws + 67108864   (262144 u16)
//   Wt_lo  = ws + 67371008
// ---------------------------------------------------------------------------
extern "C" void kernel_launch(void* const* d_in, const int* in_sizes, int n_in,
                              void* d_out, int out_size, void* d_ws, size_t ws_size,
                              hipStream_t stream) {
  const float* h     = (const float*)d_in[1];
  const float* W     = (const float*)d_in[2];
  const float* bias  = (const float*)d_in[3];
  const float* adj   = (const float*)d_in[4];
  const float* gamma = (const float*)d_in[5];
  const float* beta  = (const float*)d_in[6];
  float* out = (float*)d_out;

  unsigned short* ws = (unsigned short*)d_ws;
  unsigned short* adj_bf = ws;
  unsigned short* ob     = ws + 16777216;
  unsigned short* hp_hi  = ws + 33554432;
  unsigned short* hp_lo  = ws + 50331648;
  unsigned short* Wt_hi  = ws + 67108864;
  unsigned short* Wt_lo  = ws + 67371008;

  cast_split_Wt<<<1024, 256, 0, stream>>>(W, Wt_hi, Wt_lo);
  cast_adj<<<128, 256, 0, stream>>>(adj, adj_bf);
  proj_gemm<<<1024, 256, 0, stream>>>(h, Wt_hi, Wt_lo, bias, hp_hi, hp_lo);
  attn_kernel<<<1024, 256, 0, stream>>>(hp_hi, hp_lo, adj_bf, ob);
  ln_gelu_kernel<<<8192, 256, 0, stream>>>(ob, out, gamma, beta);
}

// Round 18
// 179.604 us; speedup vs baseline: 1.2923x; 1.0359x over previous
//
#include <hip/hip_runtime.h>
#include <stdint.h>

// ---------------------------------------------------------------------------
// GraphAttentionLayer fused pipeline, MI355X (gfx950)
// B=64 S=512 C=512 H=4 D=128.  Split-bf16 (hi+lo) 3-term MFMA for GEMM/QK^T.
// Round 18: attn kv-tile 32 -> 64.  Identical per-work math; 8 loop iters
// instead of 16 halves barrier pairs + drains + per-tile overhead, and
// doubles ILP run length between syncs.  LDS 64KB (2 x 32KB buffers),
// still 2 blocks/CU.  proj (r17 counted-vmcnt) / ln / casts frozen.
// ---------------------------------------------------------------------------

typedef float  f32x4   __attribute__((ext_vector_type(4)));
typedef short  bf16x8  __attribute__((ext_vector_type(8)));
typedef unsigned short ushort8 __attribute__((ext_vector_type(8)));
typedef unsigned int   uint2v  __attribute__((ext_vector_type(2)));

#define GLD16(src, dst)                                                        \
  __builtin_amdgcn_global_load_lds(                                            \
      (const __attribute__((address_space(1))) void*)(src),                    \
      (__attribute__((address_space(3))) void*)(dst), 16, 0, 0)

__device__ __forceinline__ unsigned short f32_to_bf16(float x) {
  union { float f; unsigned int u; } v; v.f = x;
  unsigned int r = v.u + 0x7FFFu + ((v.u >> 16) & 1u);
  return (unsigned short)(r >> 16);
}
__device__ __forceinline__ float bf16_to_f32(unsigned int h) {
  union { float f; unsigned int u; } v; v.u = h << 16;
  return v.f;
}
__device__ __forceinline__ f32x4 mfma16(bf16x8 a, bf16x8 b, f32x4 c) {
  return __builtin_amdgcn_mfma_f32_16x16x32_bf16(a, b, c, 0, 0, 0);
}
__device__ __forceinline__ float bperm_f(int srcLane, float v) {
  return __int_as_float(__builtin_amdgcn_ds_bpermute(srcLane << 2, __float_as_int(v)));
}
// HW transpose read, canonical per-lane b64 address (base + lane*8B).
__device__ __forceinline__ uint2v tr_read(const unsigned short* p) {
  uint2v r;
  asm volatile("ds_read_b64_tr_b16 %0, %1"
               : "=v"(r)
               : "v"((const __attribute__((address_space(3))) void*)p)
               : "memory");
  return r;
}

// ---------------------------------------------------------------------------
// Kernel 2: W [H,C,D] fp32 -> Wt_hi/lo [H,D,C] bf16 (transposed per head).
// ---------------------------------------------------------------------------
__global__ __launch_bounds__(256) void cast_split_Wt(
    const float* __restrict__ W, unsigned short* __restrict__ whi,
    unsigned short* __restrict__ wlo) {
  int o = blockIdx.x * 256 + threadIdx.x;      // [0, 4*128*512)
  int hd = o >> 16;                             // head
  int rem = o & 65535;
  int d = rem >> 9;                             // [0,128)
  int c = rem & 511;                            // [0,512)
  float v = W[((size_t)(hd * 512 + c)) * 128 + d];
  unsigned short h0 = f32_to_bf16(v);
  whi[o] = h0;
  wlo[o] = f32_to_bf16(v - bf16_to_f32(h0));
}

// ---------------------------------------------------------------------------
// Kernel 2b: adj (fp32) -> bf16 (exact for 0/1 masks).  8 elems/thread.
// ---------------------------------------------------------------------------
__global__ __launch_bounds__(256) void cast_adj(
    const float* __restrict__ src, unsigned short* __restrict__ dst) {
  size_t i = ((size_t)blockIdx.x * 256 + threadIdx.x) * 8;
  f32x4 a = *(const f32x4*)(src + i);
  f32x4 b = *(const f32x4*)(src + i + 4);
  ushort8 o;
#pragma unroll
  for (int e = 0; e < 4; ++e) {
    o[e] = f32_to_bf16(a[e]);
    o[4 + e] = f32_to_bf16(b[e]);
  }
  *(ushort8*)(dst + i) = o;
}

// ---------------------------------------------------------------------------
// Kernel 3: FUSED cast+projection GEMM  hp = split(h) @ Wall + bias
// (r17 counted-vmcnt pipeline, unchanged).
// ---------------------------------------------------------------------------
__global__ __launch_bounds__(256, 2) void proj_gemm(
    const float* __restrict__ hsrc,
    const unsigned short* __restrict__ whi, const unsigned short* __restrict__ wlo,
    const float* __restrict__ bias, unsigned short* __restrict__ hp_hi,
    unsigned short* __restrict__ hp_lo) {
  int bid = blockIdx.x;
  int swz = (bid & 7) * 128 + (bid >> 3);       // XCD-contiguous work chunks
  int nt = swz & 3, mt = swz >> 2;
  int m0 = mt * 128, n0 = nt * 128;             // n-tile == head nt

  __shared__ alignas(16) unsigned short Ah[4096], Al[4096], Bh[4096], Bl[4096];

  int tid = threadIdx.x, wv = tid >> 6, lane = tid & 63;
  int l15 = lane & 15, l4 = lane >> 4;
  int wr = wv >> 1, wc = wv & 1;
  int arow = tid >> 3;                          // A-stage: 0..31 (+j*32)
  int acol = (tid & 7) * 4;                     // A-stage f32 col

  f32x4 acc[4][4];
#pragma unroll
  for (int a = 0; a < 4; ++a)
#pragma unroll
    for (int b = 0; b < 4; ++b) acc[a][b] = (f32x4){0.f, 0.f, 0.f, 0.f};

  f32x4 areg[4];
#pragma unroll
  for (int j = 0; j < 4; ++j)
    areg[j] = *(const f32x4*)(hsrc + (size_t)(m0 + j * 32 + arow) * 512 + acol);

  for (int ks = 0; ks < 16; ++ks) {
    int k0 = ks * 32;
    for (int i = wv; i < 16; i += 4) {
      int grp = i >> 3, j = i & 7;
      int row = j * 16 + (lane >> 2);
      int off = (lane & 3) * 16;
      int sw = ((row >> 1) & 3) << 4;
      const unsigned short* sb = grp ? wlo : whi;
      unsigned short* db = grp ? Bl : Bh;
      GLD16((const char*)sb + ((size_t)(nt * 128 + row) * 512 + k0) * 2 + (off ^ sw),
            db + j * 512);
    }
#pragma unroll
    for (int j = 0; j < 4; ++j) {
      int r = j * 32 + arow;
      f32x4 x = areg[j];
      unsigned ua = __float_as_uint(x[0]), ub = __float_as_uint(x[1]);
      unsigned uc = __float_as_uint(x[2]), ud = __float_as_uint(x[3]);
      uint2 ph, pl;
      ph.x = (ua >> 16) | (ub & 0xFFFF0000u);
      ph.y = (uc >> 16) | (ud & 0xFFFF0000u);
      float ra = x[0] - __uint_as_float(ua & 0xFFFF0000u);
      float rb = x[1] - __uint_as_float(ub & 0xFFFF0000u);
      float rc = x[2] - __uint_as_float(uc & 0xFFFF0000u);
      float rd = x[3] - __uint_as_float(ud & 0xFFFF0000u);
      pl.x = (__float_as_uint(ra) >> 16) | (__float_as_uint(rb) & 0xFFFF0000u);
      pl.y = (__float_as_uint(rc) >> 16) | (__float_as_uint(rd) & 0xFFFF0000u);
      int boff = r * 64 + ((acol * 2) ^ (((r >> 1) & 3) << 4));
      *(uint2*)((char*)Ah + boff) = ph;
      *(uint2*)((char*)Al + boff) = pl;
    }
    if (ks < 15) {
#pragma unroll
      for (int j = 0; j < 4; ++j)
        areg[j] = *(const f32x4*)(hsrc + (size_t)(m0 + j * 32 + arow) * 512 +
                                  k0 + 32 + acol);
    }
    if (ks < 15) {
      asm volatile("s_waitcnt vmcnt(4) lgkmcnt(0)" ::: "memory");
    } else {
      asm volatile("s_waitcnt vmcnt(0) lgkmcnt(0)" ::: "memory");
    }
    __builtin_amdgcn_s_barrier();
    __builtin_amdgcn_sched_barrier(0);

    bf16x8 fah[4], fal[4], fbh[4], fbl[4];
#pragma unroll
    for (int f = 0; f < 4; ++f) {
      int mr = wr * 64 + f * 16 + l15;
      int aadr = mr * 64 + ((16 * l4) ^ (((mr >> 1) & 3) << 4));
      fah[f] = *(const bf16x8*)((const char*)Ah + aadr);
      fal[f] = *(const bf16x8*)((const char*)Al + aadr);
      int nr = wc * 64 + f * 16 + l15;
      int badr = nr * 64 + ((16 * l4) ^ (((nr >> 1) & 3) << 4));
      fbh[f] = *(const bf16x8*)((const char*)Bh + badr);
      fbl[f] = *(const bf16x8*)((const char*)Bl + badr);
    }
#pragma unroll
    for (int a = 0; a < 4; ++a)
#pragma unroll
      for (int b = 0; b < 4; ++b) {
        acc[a][b] = mfma16(fah[a], fbh[b], acc[a][b]);
        acc[a][b] = mfma16(fah[a], fbl[b], acc[a][b]);
        acc[a][b] = mfma16(fal[a], fbh[b], acc[a][b]);
      }
    asm volatile("s_waitcnt lgkmcnt(0)" ::: "memory");
    __builtin_amdgcn_s_barrier();
    __builtin_amdgcn_sched_barrier(0);
  }

  __syncthreads();   // full drain before epilogue reuses Ah/Al

#pragma unroll
  for (int a = 0; a < 4; ++a) {
    __syncthreads();
#pragma unroll
    for (int b = 0; b < 4; ++b) {
      int cloc = wc * 64 + b * 16 + l15;
      float bv = bias[n0 + cloc];
#pragma unroll
      for (int r = 0; r < 4; ++r) {
        int rloc = wr * 16 + 4 * l4 + r;
        float v = acc[a][b][r] + bv;
        unsigned short hh = f32_to_bf16(v);
        Ah[rloc * 128 + cloc] = hh;
        Al[rloc * 128 + cloc] = f32_to_bf16(v - bf16_to_f32(hh));
      }
    }
    __syncthreads();
    int rr = tid >> 3, c16 = (tid & 7) * 16;
    int mg = m0 + (rr >> 4) * 64 + a * 16 + (rr & 15);
    bf16x8 vh0 = *(const bf16x8*)(Ah + rr * 128 + c16);
    bf16x8 vh1 = *(const bf16x8*)(Ah + rr * 128 + c16 + 8);
    bf16x8 vl0 = *(const bf16x8*)(Al + rr * 128 + c16);
    bf16x8 vl1 = *(const bf16x8*)(Al + rr * 128 + c16 + 8);
    *(bf16x8*)(hp_hi + (size_t)mg * 512 + n0 + c16) = vh0;
    *(bf16x8*)(hp_hi + (size_t)mg * 512 + n0 + c16 + 8) = vh1;
    *(bf16x8*)(hp_lo + (size_t)mg * 512 + n0 + c16) = vl0;
    *(bf16x8*)(hp_lo + (size_t)mg * 512 + n0 + c16 + 8) = vl1;
  }
}

// ---------------------------------------------------------------------------
// Kernel 5: flash attention, q-tile 128, kv-tile 64.  4 waves x 32 q (nf).
// Buffer (32KB): K_hi [2 kvh][8 sd][32 kv][16 d] @ +0, K_lo @ +8192 u16.
// Double-buffered (64KB total).  8 loop iterations, one barrier each.
// QK^T 3-term; PV single-term trunc-bf16(P) @ V_hi via tr_read per kvh.
// bf16 adj in, bf16 out.  2 blocks/CU.
// ---------------------------------------------------------------------------
__global__ __launch_bounds__(256, 2) void attn_kernel(
    const unsigned short* __restrict__ hp_hi, const unsigned short* __restrict__ hp_lo,
    const unsigned short* __restrict__ adjb, unsigned short* __restrict__ ob) {
  int bid = blockIdx.x;
  int swz = (bid & 7) * 128 + (bid >> 3);       // 4 q-tiles of one (b,h) per XCD
  int qt = swz & 3;
  int hd = (swz >> 2) & 3;
  int bb = swz >> 4;
  int q0 = qt * 128;

  __shared__ alignas(16) unsigned short SM[32768];     // 64 KB -> 2 blocks/CU
  // buf0 @0, buf1 @16384 (u16).  Within buf: K_hi @0 (16 subtiles), K_lo @8192.

  int tid = threadIdx.x, w = tid >> 6, lane = tid & 63;
  int l15 = lane & 15, l4 = lane >> 4;
  int qgb = q0 + w * 32 + l15;                  // + nf*16 for the softmax row

  // Q fragments (B-operand: n=q at l&15, k=d contiguous), hi+lo, 2 nf sets
  bf16x8 qh[2][4], ql[2][4];
#pragma unroll
  for (int nf = 0; nf < 2; ++nf) {
    size_t base = ((size_t)bb * 512 + qgb + nf * 16) * 512 + hd * 128 + 8 * l4;
#pragma unroll
    for (int ds = 0; ds < 4; ++ds) {
      qh[nf][ds] = *(const bf16x8*)(hp_hi + base + ds * 32);
      ql[nf][ds] = *(const bf16x8*)(hp_lo + base + ds * 32);
    }
  }

  f32x4 o[2][8];
#pragma unroll
  for (int nf = 0; nf < 2; ++nf)
#pragma unroll
    for (int vf = 0; vf < 8; ++vf) o[nf][vf] = (f32x4){0.f, 0.f, 0.f, 0.f};
  float m_run[2] = {-3.0e38f, -3.0e38f};
  float l_run[2] = {0.f, 0.f};

  // staging: wave (w&2 ? lo : hi), kvh = w&1, 8 subtiles sd=0..7
  const unsigned short* ssb = (w & 2) ? hp_lo : hp_hi;
  int sdst = ((w & 2) ? 8192 : 0) + (w & 1) * 4096;   // u16 offset in buffer
  int skvh = (w & 1) * 32;
  int skv = lane >> 1, sdh = lane & 1;

  // ---- prologue: stage K[0..63] into buf0
  {
    size_t rowb = ((size_t)(bb * 512 + skvh + skv)) * 1024 + hd * 256 + sdh * 16;
#pragma unroll
    for (int sd = 0; sd < 8; ++sd)
      GLD16((const char*)ssb + rowb + sd * 32, SM + sdst + sd * 512);
  }
  asm volatile("s_waitcnt vmcnt(0)" ::: "memory");
  __syncthreads();

  for (int t = 0; t < 8; ++t) {
    int kv0 = t * 64;
    const unsigned short* Kb = SM + ((t & 1) << 14);
    const unsigned short* Khi = Kb;
    const unsigned short* Klo = Kb + 8192;

    // ---- stage next 64-kv tile into the other buffer
    if (t < 7) {
      unsigned short* Nb = SM + (((t + 1) & 1) << 14) + sdst;
      size_t rowb = ((size_t)(bb * 512 + kv0 + 64 + skvh + skv)) * 1024 +
                    hd * 256 + sdh * 16;
#pragma unroll
      for (int sd = 0; sd < 8; ++sd)
        GLD16((const char*)ssb + rowb + sd * 32, Nb + sd * 512);
    }
    // adj loads early (bf16): group m covers kv = m*16 + 4*l4 + r
    uint2 ua[2][4];
#pragma unroll
    for (int nf = 0; nf < 2; ++nf) {
      const unsigned short* ab = adjb + (size_t)(qgb + nf * 16) * 512 + kv0;
#pragma unroll
      for (int m = 0; m < 4; ++m)
        ua[nf][m] = *(const uint2*)(ab + m * 16 + 4 * l4);
    }

    // ---- QK^T (swapped, 3-term): K frags read once, serve both nf
    f32x4 sc[2][4];
#pragma unroll
    for (int nf = 0; nf < 2; ++nf)
#pragma unroll
      for (int m = 0; m < 4; ++m) sc[nf][m] = (f32x4){0.f, 0.f, 0.f, 0.f};
#pragma unroll
    for (int kvh = 0; kvh < 2; ++kvh) {
#pragma unroll
      for (int ds = 0; ds < 4; ++ds) {
        int boff = (kvh * 8 + 2 * ds + (l4 >> 1)) * 1024 + 16 * (l4 & 1);
        int a0 = boff + l15 * 32;
        int a1 = boff + (16 + l15) * 32;
        bf16x8 kh0 = *(const bf16x8*)((const char*)Khi + a0);
        bf16x8 kl0 = *(const bf16x8*)((const char*)Klo + a0);
        bf16x8 kh1 = *(const bf16x8*)((const char*)Khi + a1);
        bf16x8 kl1 = *(const bf16x8*)((const char*)Klo + a1);
        int m0i = kvh * 2, m1i = kvh * 2 + 1;
#pragma unroll
        for (int nf = 0; nf < 2; ++nf) {
          sc[nf][m0i] = mfma16(kh0, qh[nf][ds], sc[nf][m0i]);
          sc[nf][m1i] = mfma16(kh1, qh[nf][ds], sc[nf][m1i]);
          sc[nf][m0i] = mfma16(kh0, ql[nf][ds], sc[nf][m0i]);
          sc[nf][m1i] = mfma16(kh1, ql[nf][ds], sc[nf][m1i]);
          sc[nf][m0i] = mfma16(kl0, qh[nf][ds], sc[nf][m0i]);
          sc[nf][m1i] = mfma16(kl1, qh[nf][ds], sc[nf][m1i]);
        }
      }
    }

    // ---- adj multiply + online softmax + pack, per nf
    union PU { bf16x8 v; unsigned u[4]; } pah[2][2];  // [nf][kvh]
#pragma unroll
    for (int nf = 0; nf < 2; ++nf) {
      float p[4][4];
      float tm = -3.0e38f;
#pragma unroll
      for (int m = 0; m < 4; ++m) {
        f32x4 av;
        av[0] = bf16_to_f32(ua[nf][m].x & 0xFFFFu);
        av[1] = bf16_to_f32(ua[nf][m].x >> 16);
        av[2] = bf16_to_f32(ua[nf][m].y & 0xFFFFu);
        av[3] = bf16_to_f32(ua[nf][m].y >> 16);
#pragma unroll
        for (int r = 0; r < 4; ++r) {
          p[m][r] = sc[nf][m][r] * av[r];
          tm = fmaxf(tm, p[m][r]);
        }
      }
      tm = fmaxf(tm, __shfl_xor(tm, 16));
      tm = fmaxf(tm, __shfl_xor(tm, 32));
      if (__any(tm > m_run[nf] + 8.0f)) {       // T13 defer-rescale
        float mn = fmaxf(m_run[nf], tm);
        float scl = __expf(m_run[nf] - mn);
        m_run[nf] = mn;
        l_run[nf] *= scl;
        f32x4 s4;
#pragma unroll
        for (int r = 0; r < 4; ++r) s4[r] = bperm_f(4 * l4 + r, scl);
#pragma unroll
        for (int vf = 0; vf < 8; ++vf)
#pragma unroll
          for (int r = 0; r < 4; ++r) o[nf][vf][r] *= s4[r];
      }
      float ps = 0.f;
#pragma unroll
      for (int m = 0; m < 4; ++m)
#pragma unroll
        for (int r = 0; r < 4; ++r) {
          p[m][r] = __expf(p[m][r] - m_run[nf]);
          ps += p[m][r];
        }
      ps += __shfl_xor(ps, 16);
      ps += __shfl_xor(ps, 32);
      l_run[nf] += ps;
      // pack per kvh: pi slots e<4 from m=2kvh, e>=4 from m=2kvh+1
#pragma unroll
      for (int kvh = 0; kvh < 2; ++kvh)
#pragma unroll
        for (int i = 0; i < 4; ++i) {
          float fa = (i < 2) ? p[kvh * 2][2 * i] : p[kvh * 2 + 1][2 * (i - 2)];
          float fb = (i < 2) ? p[kvh * 2][2 * i + 1]
                             : p[kvh * 2 + 1][2 * (i - 2) + 1];
          pah[nf][kvh].u[i] = (__float_as_uint(fa) >> 16) |
                              (__float_as_uint(fb) & 0xFFFF0000u);
        }
    }

    // ---- O += P @ V_hi per kvh: tr_read 16, lgkm drain, 16 MFMA
#pragma unroll
    for (int kvh = 0; kvh < 2; ++kvh) {
      const unsigned short* trb = Khi + kvh * 4096 + lane * 4;
      union VU { bf16x8 v; uint2v u2[2]; } vh[8];
#pragma unroll
      for (int vf = 0; vf < 8; ++vf) {
        vh[vf].u2[0] = tr_read(trb + vf * 512);
        vh[vf].u2[1] = tr_read(trb + vf * 512 + 256);
      }
      asm volatile("s_waitcnt lgkmcnt(0)" ::: "memory");
      __builtin_amdgcn_sched_barrier(0);
#pragma unroll
      for (int vf = 0; vf < 8; ++vf) {
        o[0][vf] = mfma16(pah[0][kvh].v, vh[vf].v, o[0][vf]);
        o[1][vf] = mfma16(pah[1][kvh].v, vh[vf].v, o[1][vf]);
      }
    }
    asm volatile("s_waitcnt vmcnt(0) lgkmcnt(0)" ::: "memory");
    __syncthreads();   // next tile staged+visible; WAR turnover on buf[t&1]
  }

  // ---- epilogue: 2 passes (nf), wave-private LDS chunk, coalesced bf16 out
#pragma unroll
  for (int nf = 0; nf < 2; ++nf) {
    float rinv = 1.0f / l_run[nf];
    f32x4 r4;
#pragma unroll
    for (int r = 0; r < 4; ++r) r4[r] = bperm_f(4 * l4 + r, rinv);
    float* wbase = (float*)SM + w * 2048;       // [16][128] f32 per wave
#pragma unroll
    for (int vf = 0; vf < 8; ++vf)
#pragma unroll
      for (int r = 0; r < 4; ++r)
        wbase[(4 * l4 + r) * 128 + vf * 16 + l15] = o[nf][vf][r] * r4[r];
    __syncthreads();
#pragma unroll
    for (int p = 0; p < 4; ++p) {
      int row = p * 4 + l4;
      f32x4 v0 = *(const f32x4*)(wbase + row * 128 + l15 * 8);
      f32x4 v1 = *(const f32x4*)(wbase + row * 128 + l15 * 8 + 4);
      ushort8 o8;
#pragma unroll
      for (int e = 0; e < 4; ++e) {
        o8[e] = f32_to_bf16(v0[e]);
        o8[4 + e] = f32_to_bf16(v1[e]);
      }
      size_t mg = (size_t)bb * 512 + q0 + w * 32 + nf * 16 + row;
      *(ushort8*)(ob + mg * 512 + hd * 128 + l15 * 8) = o8;
    }
    __syncthreads();
  }
}

// ---------------------------------------------------------------------------
// Kernel 6: LayerNorm (over C=512) + exact-erf GELU.  bf16 in, fp32 out.
// ---------------------------------------------------------------------------
__global__ __launch_bounds__(256) void ln_gelu_kernel(
    const unsigned short* __restrict__ in, float* __restrict__ outp,
    const float* __restrict__ gamma, const float* __restrict__ beta) {
  int w = threadIdx.x >> 6, lane = threadIdx.x & 63;
  size_t row = (size_t)blockIdx.x * 4 + w;
  ushort8 v = *(const ushort8*)(in + row * 512 + lane * 8);
  float x[8];
#pragma unroll
  for (int e = 0; e < 8; ++e) x[e] = bf16_to_f32((unsigned int)(unsigned short)v[e]);
  float s = 0.f;
#pragma unroll
  for (int e = 0; e < 8; ++e) s += x[e];
#pragma unroll
  for (int off = 32; off >= 1; off >>= 1) s += __shfl_xor(s, off);
  float mu = s * (1.0f / 512.0f);
  float vs = 0.f;
#pragma unroll
  for (int e = 0; e < 8; ++e) {
    float d = x[e] - mu; vs += d * d;
  }
#pragma unroll
  for (int off = 32; off >= 1; off >>= 1) vs += __shfl_xor(vs, off);
  float rs = rsqrtf(vs * (1.0f / 512.0f) + 1e-5f);
  f32x4 g0 = *(const f32x4*)(gamma + lane * 8);
  f32x4 g1 = *(const f32x4*)(gamma + lane * 8 + 4);
  f32x4 b0 = *(const f32x4*)(beta + lane * 8);
  f32x4 b1 = *(const f32x4*)(beta + lane * 8 + 4);
  f32x4 y0, y1;
#pragma unroll
  for (int e = 0; e < 4; ++e) {
    float y = (x[e] - mu) * rs * g0[e] + b0[e];
    y0[e] = 0.5f * y * (1.0f + erff(y * 0.70710678118654752f));
    float z = (x[4 + e] - mu) * rs * g1[e] + b1[e];
    y1[e] = 0.5f * z * (1.0f + erff(z * 0.70710678118654752f));
  }
  float* p = outp + row * 512 + lane * 8;
  *(f32x4*)p = y0;
  *(f32x4*)(p + 4) = y1;
}

// ---------------------------------------------------------------------------
// Host launcher.  Inputs: [0]=t [1]=h [2]=W [3]=b [4]=adj [5]=gamma [6]=beta
// Workspace (~129 MB):
//   adj_bf = ws + 0          (262144 u16)
//   ob     = ws + 16777216   (16.7M u16, bf16 attn out)
//   hp_hi  = ws + 33554432
//   hp_lo  = ws + 50331648
//   Wt_hi  = ws + 67108864   (262144 u16)
//   Wt_lo  = ws + 67371008
// ---------------------------------------------------------------------------
extern "C" void kernel_launch(void* const* d_in, const int* in_sizes, int n_in,
                              void* d_out, int out_size, void* d_ws, size_t ws_size,
                              hipStream_t stream) {
  const float* h     = (const float*)d_in[1];
  const float* W     = (const float*)d_in[2];
  const float* bias  = (const float*)d_in[3];
  const float* adj   = (const float*)d_in[4];
  const float* gamma = (const float*)d_in[5];
  const float* beta  = (const float*)d_in[6];
  float* out = (float*)d_out;

  unsigned short* ws = (unsigned short*)d_ws;
  unsigned short* adj_bf = ws;
  unsigned short* ob     = ws + 16777216;
  unsigned short* hp_hi  = ws + 33554432;
  unsigned short* hp_lo  = ws + 50331648;
  unsigned short* Wt_hi  = ws + 67108864;
  unsigned short* Wt_lo  = ws + 67371008;

  cast_split_Wt<<<1024, 256, 0, stream>>>(W, Wt_hi, Wt_lo);
  cast_adj<<<128, 256, 0, stream>>>(adj, adj_bf);
  proj_gemm<<<1024, 256, 0, stream>>>(h, Wt_hi, Wt_lo, bias, hp_hi, hp_lo);
  attn_kernel<<<1024, 256, 0, stream>>>(hp_hi, hp_lo, adj_bf, ob);
  ln_gelu_kernel<<<8192, 256, 0, stream>>>(ob, out, gamma, beta);
}

// Round 20
// 172.977 us; speedup vs baseline: 1.3418x; 1.0383x over previous
//
#include <hip/hip_runtime.h>
#include <stdint.h>

// ---------------------------------------------------------------------------
// GraphAttentionLayer fused pipeline, MI355X (gfx950)
// B=64 S=512 C=512 H=4 D=128.  Split-bf16 (hi+lo) 3-term MFMA for GEMM/QK^T.
// Round 20: r19 with the pk2 compile fix (return uint2 by value instead of
// binding references to vector elements).  proj BK=64 (8 K-steps, canonical
// (row&7)<<4 swizzle, counted-vmcnt(8) A-prefetch).  attn: T5 setprio around
// MFMA clusters; otherwise r18 (q-tile 128, kv-tile 64).  ln/casts frozen.
// ---------------------------------------------------------------------------

typedef float  f32x4   __attribute__((ext_vector_type(4)));
typedef short  bf16x8  __attribute__((ext_vector_type(8)));
typedef unsigned short ushort8 __attribute__((ext_vector_type(8)));
typedef unsigned int   uint2v  __attribute__((ext_vector_type(2)));
typedef unsigned int   uint4v  __attribute__((ext_vector_type(4)));

#define GLD16(src, dst)                                                        \
  __builtin_amdgcn_global_load_lds(                                            \
      (const __attribute__((address_space(1))) void*)(src),                    \
      (__attribute__((address_space(3))) void*)(dst), 16, 0, 0)

__device__ __forceinline__ unsigned short f32_to_bf16(float x) {
  union { float f; unsigned int u; } v; v.f = x;
  unsigned int r = v.u + 0x7FFFu + ((v.u >> 16) & 1u);
  return (unsigned short)(r >> 16);
}
__device__ __forceinline__ float bf16_to_f32(unsigned int h) {
  union { float f; unsigned int u; } v; v.u = h << 16;
  return v.f;
}
__device__ __forceinline__ f32x4 mfma16(bf16x8 a, bf16x8 b, f32x4 c) {
  return __builtin_amdgcn_mfma_f32_16x16x32_bf16(a, b, c, 0, 0, 0);
}
__device__ __forceinline__ float bperm_f(int srcLane, float v) {
  return __int_as_float(__builtin_amdgcn_ds_bpermute(srcLane << 2, __float_as_int(v)));
}
// Trunc-split pair pack: two f32 -> {hi 2xbf16, lo 2xbf16} as uint2.
__device__ __forceinline__ uint2 pk2(float fa, float fb) {
  unsigned ua = __float_as_uint(fa), ub = __float_as_uint(fb);
  uint2 r;
  r.x = (ua >> 16) | (ub & 0xFFFF0000u);
  float ra = fa - __uint_as_float(ua & 0xFFFF0000u);
  float rb = fb - __uint_as_float(ub & 0xFFFF0000u);
  r.y = (__float_as_uint(ra) >> 16) | (__float_as_uint(rb) & 0xFFFF0000u);
  return r;
}
// HW transpose read, canonical per-lane b64 address (base + lane*8B).
__device__ __forceinline__ uint2v tr_read(const unsigned short* p) {
  uint2v r;
  asm volatile("ds_read_b64_tr_b16 %0, %1"
               : "=v"(r)
               : "v"((const __attribute__((address_space(3))) void*)p)
               : "memory");
  return r;
}

// ---------------------------------------------------------------------------
// Kernel 2: W [H,C,D] fp32 -> Wt_hi/lo [H,D,C] bf16 (transposed per head).
// ---------------------------------------------------------------------------
__global__ __launch_bounds__(256) void cast_split_Wt(
    const float* __restrict__ W, unsigned short* __restrict__ whi,
    unsigned short* __restrict__ wlo) {
  int o = blockIdx.x * 256 + threadIdx.x;      // [0, 4*128*512)
  int hd = o >> 16;                             // head
  int rem = o & 65535;
  int d = rem >> 9;                             // [0,128)
  int c = rem & 511;                            // [0,512)
  float v = W[((size_t)(hd * 512 + c)) * 128 + d];
  unsigned short h0 = f32_to_bf16(v);
  whi[o] = h0;
  wlo[o] = f32_to_bf16(v - bf16_to_f32(h0));
}

// ---------------------------------------------------------------------------
// Kernel 2b: adj (fp32) -> bf16 (exact for 0/1 masks).  8 elems/thread.
// ---------------------------------------------------------------------------
__global__ __launch_bounds__(256) void cast_adj(
    const float* __restrict__ src, unsigned short* __restrict__ dst) {
  size_t i = ((size_t)blockIdx.x * 256 + threadIdx.x) * 8;
  f32x4 a = *(const f32x4*)(src + i);
  f32x4 b = *(const f32x4*)(src + i + 4);
  ushort8 o;
#pragma unroll
  for (int e = 0; e < 4; ++e) {
    o[e] = f32_to_bf16(a[e]);
    o[4 + e] = f32_to_bf16(b[e]);
  }
  *(ushort8*)(dst + i) = o;
}

// ---------------------------------------------------------------------------
// Kernel 3: FUSED cast+projection GEMM  hp = split(h) @ Wall + bias.
// BK=64: [128 rows][64 k] bf16 tiles (row stride 128B, XOR swizzle
// (row&7)<<4).  8 K-steps, 2 barriers each.  B via GLD16 (pre-swizzled src);
// A reg-staged from f32 h, trunc-split, ds_write_b128; A[ks+1] prefetched,
// counted vmcnt(8) drain keeps it in flight across the barrier.
// ---------------------------------------------------------------------------
__global__ __launch_bounds__(256, 2) void proj_gemm(
    const float* __restrict__ hsrc,
    const unsigned short* __restrict__ whi, const unsigned short* __restrict__ wlo,
    const float* __restrict__ bias, unsigned short* __restrict__ hp_hi,
    unsigned short* __restrict__ hp_lo) {
  int bid = blockIdx.x;
  int swz = (bid & 7) * 128 + (bid >> 3);       // XCD-contiguous work chunks
  int nt = swz & 3, mt = swz >> 2;
  int m0 = mt * 128, n0 = nt * 128;             // n-tile == head nt

  __shared__ alignas(16) unsigned short Ah[8192], Al[8192], Bh[8192], Bl[8192];

  int tid = threadIdx.x, wv = tid >> 6, lane = tid & 63;
  int l15 = lane & 15, l4 = lane >> 4;
  int wr = wv >> 1, wc = wv & 1;
  int arow = tid >> 3;                          // 0..31
  int acol8 = (tid & 7) * 8;                    // f32 col base (8 per thread)

  f32x4 acc[4][4];
#pragma unroll
  for (int a = 0; a < 4; ++a)
#pragma unroll
    for (int b = 0; b < 4; ++b) acc[a][b] = (f32x4){0.f, 0.f, 0.f, 0.f};

  // ---- prologue: A[0] into regs (8 x f32x4)
  f32x4 areg[4][2];
#pragma unroll
  for (int j = 0; j < 4; ++j) {
    const float* rp = hsrc + (size_t)(m0 + j * 32 + arow) * 512 + acol8;
    areg[j][0] = *(const f32x4*)rp;
    areg[j][1] = *(const f32x4*)(rp + 4);
  }

  for (int ks = 0; ks < 8; ++ks) {
    int k0 = ks * 64;
    // 1) B staging via GLD16: 32 x 1KB chunks over 4 waves (oldest vm ops)
    for (int i = wv; i < 32; i += 4) {
      int grp = i >> 4, j = i & 15;
      int row = j * 8 + (lane >> 3);
      int off = (lane & 7) * 16;
      int sw = (row & 7) << 4;
      const unsigned short* sb = grp ? wlo : whi;
      unsigned short* db = grp ? Bl : Bh;
      GLD16((const char*)sb + ((size_t)(nt * 128 + row) * 512 + k0) * 2 + (off ^ sw),
            db + j * 512);
    }
    __builtin_amdgcn_sched_barrier(0);          // pin GLD16s as oldest
    // 2) split A[ks] regs -> swizzled ds_write_b128 (hi + lo)
#pragma unroll
    for (int j = 0; j < 4; ++j) {
      int r = j * 32 + arow;
      uint4v uh, ul;
      uint2 p0 = pk2(areg[j][0][0], areg[j][0][1]);
      uint2 p1 = pk2(areg[j][0][2], areg[j][0][3]);
      uint2 p2 = pk2(areg[j][1][0], areg[j][1][1]);
      uint2 p3 = pk2(areg[j][1][2], areg[j][1][3]);
      uh[0] = p0.x; ul[0] = p0.y;
      uh[1] = p1.x; ul[1] = p1.y;
      uh[2] = p2.x; ul[2] = p2.y;
      uh[3] = p3.x; ul[3] = p3.y;
      int boff = r * 128 + ((acol8 * 2) ^ ((r & 7) << 4));
      *(uint4v*)((char*)Ah + boff) = uh;
      *(uint4v*)((char*)Al + boff) = ul;
    }
    // 3) A[ks+1] prefetch (youngest vm ops, stay in flight across barrier)
    if (ks < 7) {
#pragma unroll
      for (int j = 0; j < 4; ++j) {
        const float* rp = hsrc + (size_t)(m0 + j * 32 + arow) * 512 + k0 + 64 + acol8;
        areg[j][0] = *(const f32x4*)rp;
        areg[j][1] = *(const f32x4*)(rp + 4);
      }
    }
    // 4) counted drain: B + ds_writes done; A-prefetch (8 loads) keeps flying
    if (ks < 7) {
      asm volatile("s_waitcnt vmcnt(8) lgkmcnt(0)" ::: "memory");
    } else {
      asm volatile("s_waitcnt vmcnt(0) lgkmcnt(0)" ::: "memory");
    }
    __builtin_amdgcn_s_barrier();
    __builtin_amdgcn_sched_barrier(0);

    // 5) MFMA over the 2 k-halves of the 64-wide tile
#pragma unroll
    for (int ks2 = 0; ks2 < 2; ++ks2) {
      int kb = (ks2 * 64 + 16 * l4);
      bf16x8 fah[4], fal[4], fbh[4], fbl[4];
#pragma unroll
      for (int f = 0; f < 4; ++f) {
        int mr = wr * 64 + f * 16 + l15;
        int aadr = mr * 128 + (kb ^ ((mr & 7) << 4));
        fah[f] = *(const bf16x8*)((const char*)Ah + aadr);
        fal[f] = *(const bf16x8*)((const char*)Al + aadr);
        int nr = wc * 64 + f * 16 + l15;
        int badr = nr * 128 + (kb ^ ((nr & 7) << 4));
        fbh[f] = *(const bf16x8*)((const char*)Bh + badr);
        fbl[f] = *(const bf16x8*)((const char*)Bl + badr);
      }
#pragma unroll
      for (int a = 0; a < 4; ++a)
#pragma unroll
        for (int b = 0; b < 4; ++b) {
          acc[a][b] = mfma16(fah[a], fbh[b], acc[a][b]);
          acc[a][b] = mfma16(fah[a], fbl[b], acc[a][b]);
          acc[a][b] = mfma16(fal[a], fbh[b], acc[a][b]);
        }
    }
    // 6) WAR fence (own LDS reads done); do NOT drain vmcnt mid-loop
    asm volatile("s_waitcnt lgkmcnt(0)" ::: "memory");
    __builtin_amdgcn_s_barrier();
    __builtin_amdgcn_sched_barrier(0);
  }

  __syncthreads();   // full drain before epilogue reuses Ah/Al

  // epilogue: +bias, RNE split, LDS-staged coalesced writes of hp rows.
#pragma unroll
  for (int a = 0; a < 4; ++a) {
    __syncthreads();
#pragma unroll
    for (int b = 0; b < 4; ++b) {
      int cloc = wc * 64 + b * 16 + l15;
      float bv = bias[n0 + cloc];
#pragma unroll
      for (int r = 0; r < 4; ++r) {
        int rloc = wr * 16 + 4 * l4 + r;
        float v = acc[a][b][r] + bv;
        unsigned short hh = f32_to_bf16(v);
        Ah[rloc * 128 + cloc] = hh;
        Al[rloc * 128 + cloc] = f32_to_bf16(v - bf16_to_f32(hh));
      }
    }
    __syncthreads();
    int rr = tid >> 3, c16 = (tid & 7) * 16;
    int mg = m0 + (rr >> 4) * 64 + a * 16 + (rr & 15);
    bf16x8 vh0 = *(const bf16x8*)(Ah + rr * 128 + c16);
    bf16x8 vh1 = *(const bf16x8*)(Ah + rr * 128 + c16 + 8);
    bf16x8 vl0 = *(const bf16x8*)(Al + rr * 128 + c16);
    bf16x8 vl1 = *(const bf16x8*)(Al + rr * 128 + c16 + 8);
    *(bf16x8*)(hp_hi + (size_t)mg * 512 + n0 + c16) = vh0;
    *(bf16x8*)(hp_hi + (size_t)mg * 512 + n0 + c16 + 8) = vh1;
    *(bf16x8*)(hp_lo + (size_t)mg * 512 + n0 + c16) = vl0;
    *(bf16x8*)(hp_lo + (size_t)mg * 512 + n0 + c16 + 8) = vl1;
  }
}

// ---------------------------------------------------------------------------
// Kernel 5: flash attention, q-tile 128, kv-tile 64 (r18) + T5 setprio
// around the QK^T and PV MFMA clusters.  4 waves x 32 q (nf).  K subtiled
// [2 kvh][8 sd][32 kv][16 d] hi+lo, dbuf (64KB).  8 iters, 1 barrier each.
// ---------------------------------------------------------------------------
__global__ __launch_bounds__(256, 2) void attn_kernel(
    const unsigned short* __restrict__ hp_hi, const unsigned short* __restrict__ hp_lo,
    const unsigned short* __restrict__ adjb, unsigned short* __restrict__ ob) {
  int bid = blockIdx.x;
  int swz = (bid & 7) * 128 + (bid >> 3);       // 4 q-tiles of one (b,h) per XCD
  int qt = swz & 3;
  int hd = (swz >> 2) & 3;
  int bb = swz >> 4;
  int q0 = qt * 128;

  __shared__ alignas(16) unsigned short SM[32768];     // 64 KB -> 2 blocks/CU

  int tid = threadIdx.x, w = tid >> 6, lane = tid & 63;
  int l15 = lane & 15, l4 = lane >> 4;
  int qgb = q0 + w * 32 + l15;                  // + nf*16 for the softmax row

  bf16x8 qh[2][4], ql[2][4];
#pragma unroll
  for (int nf = 0; nf < 2; ++nf) {
    size_t base = ((size_t)bb * 512 + qgb + nf * 16) * 512 + hd * 128 + 8 * l4;
#pragma unroll
    for (int ds = 0; ds < 4; ++ds) {
      qh[nf][ds] = *(const bf16x8*)(hp_hi + base + ds * 32);
      ql[nf][ds] = *(const bf16x8*)(hp_lo + base + ds * 32);
    }
  }

  f32x4 o[2][8];
#pragma unroll
  for (int nf = 0; nf < 2; ++nf)
#pragma unroll
    for (int vf = 0; vf < 8; ++vf) o[nf][vf] = (f32x4){0.f, 0.f, 0.f, 0.f};
  float m_run[2] = {-3.0e38f, -3.0e38f};
  float l_run[2] = {0.f, 0.f};

  const unsigned short* ssb = (w & 2) ? hp_lo : hp_hi;
  int sdst = ((w & 2) ? 8192 : 0) + (w & 1) * 4096;
  int skvh = (w & 1) * 32;
  int skv = lane >> 1, sdh = lane & 1;

  {
    size_t rowb = ((size_t)(bb * 512 + skvh + skv)) * 1024 + hd * 256 + sdh * 16;
#pragma unroll
    for (int sd = 0; sd < 8; ++sd)
      GLD16((const char*)ssb + rowb + sd * 32, SM + sdst + sd * 512);
  }
  asm volatile("s_waitcnt vmcnt(0)" ::: "memory");
  __syncthreads();

  for (int t = 0; t < 8; ++t) {
    int kv0 = t * 64;
    const unsigned short* Kb = SM + ((t & 1) << 14);
    const unsigned short* Khi = Kb;
    const unsigned short* Klo = Kb + 8192;

    if (t < 7) {
      unsigned short* Nb = SM + (((t + 1) & 1) << 14) + sdst;
      size_t rowb = ((size_t)(bb * 512 + kv0 + 64 + skvh + skv)) * 1024 +
                    hd * 256 + sdh * 16;
#pragma unroll
      for (int sd = 0; sd < 8; ++sd)
        GLD16((const char*)ssb + rowb + sd * 32, Nb + sd * 512);
    }
    uint2 ua[2][4];
#pragma unroll
    for (int nf = 0; nf < 2; ++nf) {
      const unsigned short* ab = adjb + (size_t)(qgb + nf * 16) * 512 + kv0;
#pragma unroll
      for (int m = 0; m < 4; ++m)
        ua[nf][m] = *(const uint2*)(ab + m * 16 + 4 * l4);
    }

    // ---- QK^T (swapped, 3-term) — setprio(1) while the MFMA cluster runs
    f32x4 sc[2][4];
#pragma unroll
    for (int nf = 0; nf < 2; ++nf)
#pragma unroll
      for (int m = 0; m < 4; ++m) sc[nf][m] = (f32x4){0.f, 0.f, 0.f, 0.f};
    __builtin_amdgcn_s_setprio(1);
#pragma unroll
    for (int kvh = 0; kvh < 2; ++kvh) {
#pragma unroll
      for (int ds = 0; ds < 4; ++ds) {
        int boff = (kvh * 8 + 2 * ds + (l4 >> 1)) * 1024 + 16 * (l4 & 1);
        int a0 = boff + l15 * 32;
        int a1 = boff + (16 + l15) * 32;
        bf16x8 kh0 = *(const bf16x8*)((const char*)Khi + a0);
        bf16x8 kl0 = *(const bf16x8*)((const char*)Klo + a0);
        bf16x8 kh1 = *(const bf16x8*)((const char*)Khi + a1);
        bf16x8 kl1 = *(const bf16x8*)((const char*)Klo + a1);
        int m0i = kvh * 2, m1i = kvh * 2 + 1;
#pragma unroll
        for (int nf = 0; nf < 2; ++nf) {
          sc[nf][m0i] = mfma16(kh0, qh[nf][ds], sc[nf][m0i]);
          sc[nf][m1i] = mfma16(kh1, qh[nf][ds], sc[nf][m1i]);
          sc[nf][m0i] = mfma16(kh0, ql[nf][ds], sc[nf][m0i]);
          sc[nf][m1i] = mfma16(kh1, ql[nf][ds], sc[nf][m1i]);
          sc[nf][m0i] = mfma16(kl0, qh[nf][ds], sc[nf][m0i]);
          sc[nf][m1i] = mfma16(kl1, qh[nf][ds], sc[nf][m1i]);
        }
      }
    }
    __builtin_amdgcn_s_setprio(0);

    // ---- adj multiply + online softmax + pack, per nf
    union PU { bf16x8 v; unsigned u[4]; } pah[2][2];  // [nf][kvh]
#pragma unroll
    for (int nf = 0; nf < 2; ++nf) {
      float p[4][4];
      float tm = -3.0e38f;
#pragma unroll
      for (int m = 0; m < 4; ++m) {
        f32x4 av;
        av[0] = bf16_to_f32(ua[nf][m].x & 0xFFFFu);
        av[1] = bf16_to_f32(ua[nf][m].x >> 16);
        av[2] = bf16_to_f32(ua[nf][m].y & 0xFFFFu);
        av[3] = bf16_to_f32(ua[nf][m].y >> 16);
#pragma unroll
        for (int r = 0; r < 4; ++r) {
          p[m][r] = sc[nf][m][r] * av[r];
          tm = fmaxf(tm, p[m][r]);
        }
      }
      tm = fmaxf(tm, __shfl_xor(tm, 16));
      tm = fmaxf(tm, __shfl_xor(tm, 32));
      if (__any(tm > m_run[nf] + 8.0f)) {       // T13 defer-rescale
        float mn = fmaxf(m_run[nf], tm);
        float scl = __expf(m_run[nf] - mn);
        m_run[nf] = mn;
        l_run[nf] *= scl;
        f32x4 s4;
#pragma unroll
        for (int r = 0; r < 4; ++r) s4[r] = bperm_f(4 * l4 + r, scl);
#pragma unroll
        for (int vf = 0; vf < 8; ++vf)
#pragma unroll
          for (int r = 0; r < 4; ++r) o[nf][vf][r] *= s4[r];
      }
      float ps = 0.f;
#pragma unroll
      for (int m = 0; m < 4; ++m)
#pragma unroll
        for (int r = 0; r < 4; ++r) {
          p[m][r] = __expf(p[m][r] - m_run[nf]);
          ps += p[m][r];
        }
      ps += __shfl_xor(ps, 16);
      ps += __shfl_xor(ps, 32);
      l_run[nf] += ps;
#pragma unroll
      for (int kvh = 0; kvh < 2; ++kvh)
#pragma unroll
        for (int i = 0; i < 4; ++i) {
          float fa = (i < 2) ? p[kvh * 2][2 * i] : p[kvh * 2 + 1][2 * (i - 2)];
          float fb = (i < 2) ? p[kvh * 2][2 * i + 1]
                             : p[kvh * 2 + 1][2 * (i - 2) + 1];
          pah[nf][kvh].u[i] = (__float_as_uint(fa) >> 16) |
                              (__float_as_uint(fb) & 0xFFFF0000u);
        }
    }

    // ---- O += P @ V_hi per kvh (tr_read + MFMA cluster under setprio)
#pragma unroll
    for (int kvh = 0; kvh < 2; ++kvh) {
      const unsigned short* trb = Khi + kvh * 4096 + lane * 4;
      union VU { bf16x8 v; uint2v u2[2]; } vh[8];
#pragma unroll
      for (int vf = 0; vf < 8; ++vf) {
        vh[vf].u2[0] = tr_read(trb + vf * 512);
        vh[vf].u2[1] = tr_read(trb + vf * 512 + 256);
      }
      asm volatile("s_waitcnt lgkmcnt(0)" ::: "memory");
      __builtin_amdgcn_sched_barrier(0);
      __builtin_amdgcn_s_setprio(1);
#pragma unroll
      for (int vf = 0; vf < 8; ++vf) {
        o[0][vf] = mfma16(pah[0][kvh].v, vh[vf].v, o[0][vf]);
        o[1][vf] = mfma16(pah[1][kvh].v, vh[vf].v, o[1][vf]);
      }
      __builtin_amdgcn_s_setprio(0);
    }
    asm volatile("s_waitcnt vmcnt(0) lgkmcnt(0)" ::: "memory");
    __syncthreads();   // next tile staged+visible; WAR turnover on buf[t&1]
  }

  // ---- epilogue: 2 passes (nf), wave-private LDS chunk, coalesced bf16 out
#pragma unroll
  for (int nf = 0; nf < 2; ++nf) {
    float rinv = 1.0f / l_run[nf];
    f32x4 r4;
#pragma unroll
    for (int r = 0; r < 4; ++r) r4[r] = bperm_f(4 * l4 + r, rinv);
    float* wbase = (float*)SM + w * 2048;       // [16][128] f32 per wave
#pragma unroll
    for (int vf = 0; vf < 8; ++vf)
#pragma unroll
      for (int r = 0; r < 4; ++r)
        wbase[(4 * l4 + r) * 128 + vf * 16 + l15] = o[nf][vf][r] * r4[r];
    __syncthreads();
#pragma unroll
    for (int p = 0; p < 4; ++p) {
      int row = p * 4 + l4;
      f32x4 v0 = *(const f32x4*)(wbase + row * 128 + l15 * 8);
      f32x4 v1 = *(const f32x4*)(wbase + row * 128 + l15 * 8 + 4);
      ushort8 o8;
#pragma unroll
      for (int e = 0; e < 4; ++e) {
        o8[e] = f32_to_bf16(v0[e]);
        o8[4 + e] = f32_to_bf16(v1[e]);
      }
      size_t mg = (size_t)bb * 512 + q0 + w * 32 + nf * 16 + row;
      *(ushort8*)(ob + mg * 512 + hd * 128 + l15 * 8) = o8;
    }
    __syncthreads();
  }
}

// ---------------------------------------------------------------------------
// Kernel 6: LayerNorm (over C=512) + exact-erf GELU.  bf16 in, fp32 out.
// ---------------------------------------------------------------------------
__global__ __launch_bounds__(256) void ln_gelu_kernel(
    const unsigned short* __restrict__ in, float* __restrict__ outp,
    const float* __restrict__ gamma, const float* __restrict__ beta) {
  int w = threadIdx.x >> 6, lane = threadIdx.x & 63;
  size_t row = (size_t)blockIdx.x * 4 + w;
  ushort8 v = *(const ushort8*)(in + row * 512 + lane * 8);
  float x[8];
#pragma unroll
  for (int e = 0; e < 8; ++e) x[e] = bf16_to_f32((unsigned int)(unsigned short)v[e]);
  float s = 0.f;
#pragma unroll
  for (int e = 0; e < 8; ++e) s += x[e];
#pragma unroll
  for (int off = 32; off >= 1; off >>= 1) s += __shfl_xor(s, off);
  float mu = s * (1.0f / 512.0f);
  float vs = 0.f;
#pragma unroll
  for (int e = 0; e < 8; ++e) {
    float d = x[e] - mu; vs += d * d;
  }
#pragma unroll
  for (int off = 32; off >= 1; off >>= 1) vs += __shfl_xor(vs, off);
  float rs = rsqrtf(vs * (1.0f / 512.0f) + 1e-5f);
  f32x4 g0 = *(const f32x4*)(gamma + lane * 8);
  f32x4 g1 = *(const f32x4*)(gamma + lane * 8 + 4);
  f32x4 b0 = *(const f32x4*)(beta + lane * 8);
  f32x4 b1 = *(const f32x4*)(beta + lane * 8 + 4);
  f32x4 y0, y1;
#pragma unroll
  for (int e = 0; e < 4; ++e) {
    float y = (x[e] - mu) * rs * g0[e] + b0[e];
    y0[e] = 0.5f * y * (1.0f + erff(y * 0.70710678118654752f));
    float z = (x[4 + e] - mu) * rs * g1[e] + b1[e];
    y1[e] = 0.5f * z * (1.0f + erff(z * 0.70710678118654752f));
  }
  float* p = outp + row * 512 + lane * 8;
  *(f32x4*)p = y0;
  *(f32x4*)(p + 4) = y1;
}

// ---------------------------------------------------------------------------
// Host launcher.  Inputs: [0]=t [1]=h [2]=W [3]=b [4]=adj [5]=gamma [6]=beta
// Workspace (~129 MB):
//   adj_bf = ws + 0          (262144 u16)
//   ob     = ws + 16777216   (16.7M u16, bf16 attn out)
//   hp_hi  = ws + 33554432
//   hp_lo  = ws + 50331648
//   Wt_hi  = ws + 67108864   (262144 u16)
//   Wt_lo  = ws + 67371008
// ---------------------------------------------------------------------------
extern "C" void kernel_launch(void* const* d_in, const int* in_sizes, int n_in,
                              void* d_out, int out_size, void* d_ws, size_t ws_size,
                              hipStream_t stream) {
  const float* h     = (const float*)d_in[1];
  const float* W     = (const float*)d_in[2];
  const float* bias  = (const float*)d_in[3];
  const float* adj   = (const float*)d_in[4];
  const float* gamma = (const float*)d_in[5];
  const float* beta  = (const float*)d_in[6];
  float* out = (float*)d_out;

  unsigned short* ws = (unsigned short*)d_ws;
  unsigned short* adj_bf = ws;
  unsigned short* ob     = ws + 16777216;
  unsigned short* hp_hi  = ws + 33554432;
  unsigned short* hp_lo  = ws + 50331648;
  unsigned short* Wt_hi  = ws + 67108864;
  unsigned short* Wt_lo  = ws + 67371008;

  cast_split_Wt<<<1024, 256, 0, stream>>>(W, Wt_hi, Wt_lo);
  cast_adj<<<128, 256, 0, stream>>>(adj, adj_bf);
  proj_gemm<<<1024, 256, 0, stream>>>(h, Wt_hi, Wt_lo, bias, hp_hi, hp_lo);
  attn_kernel<<<1024, 256, 0, stream>>>(hp_hi, hp_lo, adj_bf, ob);
  ln_gelu_kernel<<<8192, 256, 0, stream>>>(ob, out, gamma, beta);
}